// Round 11
// baseline (405.287 us; speedup 1.0000x reference)
//
#include <hip/hip_runtime.h>

#define NB 8
#define NF 16384
#define NE 32768
#define DD 128

static constexpr int ME = NB * NE;  // 262144 edges
static constexpr int MF = NB * NF;  // 131072 faces
static constexpr int CAP = 32;      // face bucket capacity (max deg ~ Poisson(4) << 32)

typedef short bf16x8 __attribute__((ext_vector_type(8)));
typedef float f32x4 __attribute__((ext_vector_type(4)));

#define MFMA16(a, b, c) __builtin_amdgcn_mfma_f32_16x16x32_bf16((a), (b), (c), 0, 0, 0)

// hardware f32->bf16 RNE
static __device__ __forceinline__ unsigned short f2bf(float f) {
  __bf16 h = (__bf16)f;
  return __builtin_bit_cast(unsigned short, h);
}
static __device__ __forceinline__ float bf2f(unsigned short h) {
  union { unsigned u; float f; } v; v.u = ((unsigned)h) << 16;
  return v.f;
}
static __device__ __forceinline__ bf16x8 pack8(float4 a, float4 b) {
  bf16x8 r;
  r[0] = (short)f2bf(a.x); r[1] = (short)f2bf(a.y);
  r[2] = (short)f2bf(a.z); r[3] = (short)f2bf(a.w);
  r[4] = (short)f2bf(b.x); r[5] = (short)f2bf(b.y);
  r[6] = (short)f2bf(b.z); r[7] = (short)f2bf(b.w);
  return r;
}

// A/B fragment: elements j0..3 at k=kb..kb+3, j4..7 at k=kb+16..kb+19
static __device__ __forceinline__ bf16x8 ld_ab(const unsigned short* p) {
  union { unsigned long long q[2]; bf16x8 v; } u;
  u.q[0] = *(const unsigned long long*)(p);
  u.q[1] = *(const unsigned long long*)(p + 16);
  return u.v;
}
// contiguous 8 bf16 via two b64 loads (8B-aligned addresses OK)
static __device__ __forceinline__ bf16x8 ld8(const unsigned short* p) {
  union { unsigned long long q[2]; bf16x8 v; } u;
  u.q[0] = *(const unsigned long long*)(p);
  u.q[1] = *(const unsigned long long*)(p + 4);
  return u.v;
}

// tanh-form GELU via hw exp (|err vs erf-GELU| <= ~6e-4)
static __device__ __forceinline__ float gelu_fast(float x) {
  const float z = x * (1.5957691216f + 0.0713548163f * x * x);
  return __fdividef(x, 1.0f + __expf(-z));
}
static __device__ __forceinline__ float sigmoid_fast(float x) {
  return __fdividef(1.0f, 1.0f + __expf(-x));
}

// ---- merged prologue: 6 weight packs (blocks 0..959) + bucket fill (960..1983) ----
__global__ void k_prep(const float* __restrict__ w_fe1, const float* __restrict__ w_fe2,
                       const float* __restrict__ w_ge, const float* __restrict__ w_ef1,
                       const float* __restrict__ w_ef2, const float* __restrict__ w_gf,
                       unsigned short* __restrict__ W1f, unsigned short* __restrict__ W2f,
                       unsigned short* __restrict__ Wgf, unsigned short* __restrict__ Wef1,
                       unsigned short* __restrict__ Wef2, unsigned short* __restrict__ Wgff,
                       const int* __restrict__ e2f, const int* __restrict__ emask,
                       int* __restrict__ cntI, int* __restrict__ outInt) {
  const int b = blockIdx.x;
  if (b < 960) {
    const float* W; unsigned short* Wf; int K, N, base;
    if (b < 384)      { W = w_fe1; Wf = W1f;  K = 384; N = 256; base = 0; }
    else if (b < 512) { W = w_fe2; Wf = W2f;  K = 256; N = 128; base = 384; }
    else if (b < 640) { W = w_ge;  Wf = Wgf;  K = 256; N = 128; base = 512; }
    else if (b < 768) { W = w_ef1; Wf = Wef1; K = 256; N = 128; base = 640; }
    else if (b < 832) { W = w_ef2; Wf = Wef2; K = 128; N = 128; base = 768; }
    else              { W = w_gf;  Wf = Wgff; K = 256; N = 128; base = 832; }
    const int idx = (b - base) * 256 + threadIdx.x;
    const int j = idx & 7, lane = (idx >> 3) & 63, rest = idx >> 9;
    const int KS = K >> 5, ks = rest % KS, nt = rest / KS;
    const int col = nt * 16 + (lane & 15);
    const int kk = ks * 32 + ((j >> 2) << 4) + ((lane >> 4) << 2) + (j & 3);
    Wf[idx] = f2bf(W[kk * N + col]);
  } else {
    const int eg = (b - 960) * 256 + threadIdx.x;
    const int r1 = e2f[2 * eg], r2 = e2f[2 * eg + 1];
    if (!(emask[eg] != 0 && r1 >= 0 && r2 >= 0)) return;
    const int bb = eg >> 15;
    const int f1 = r1 > NF - 1 ? NF - 1 : r1;
    const int f2 = r2 > NF - 1 ? NF - 1 : r2;
    const int i1 = bb * NF + f1, i2 = bb * NF + f2;
    const int p1 = atomicAdd(cntI + i1, 1);
    if (p1 < CAP) outInt[(size_t)i1 * DD + p1] = eg;
    const int p2 = atomicAdd(cntI + i2, 1);
    if (p2 < CAP) outInt[(size_t)i2 * DD + p2] = eg;
  }
}

// ---------------- Edge kernel: proven r7/r10 alias map & barriers; phase-merged.
// 64 edges/block, 8 waves, 2 blocks/CU. 3-blk/CU variants quarantined (replay race).
// LDS pool (69376 B):
//   Xe  u16 pitch 136 @0      (17408)  E bf16
//   Xf  u16 pitch 264 @17408  (33792) -> H u16 pitch 260 -> M f32 pitch 132
//   Mb  u16 pitch 132 @51200  (16896) -> G u16 pitch 132 (after "Mb read" barrier)
//   aux @68096: f1s[64] f2s[64] validf[64]
__global__ __launch_bounds__(512, 4) void k_edge(
    const float* __restrict__ Efeat, const float* __restrict__ Ffeat,
    const int* __restrict__ e2f, const int* __restrict__ emask,
    const unsigned short* __restrict__ W1f, const float* __restrict__ b1,
    const unsigned short* __restrict__ W2f, const float* __restrict__ b2,
    const unsigned short* __restrict__ Wgf, const float* __restrict__ bg,
    const float* __restrict__ ge, const float* __restrict__ be,
    float* __restrict__ out) {
  __shared__ __align__(16) unsigned char pool[69376];
  unsigned short* Xe = (unsigned short*)pool;             // pitch 136
  unsigned short* Xf = (unsigned short*)(pool + 17408);   // pitch 264
  unsigned short* H  = (unsigned short*)(pool + 17408);   // pitch 260
  float*          M  = (float*)(pool + 17408);            // pitch 132
  unsigned short* Mb = (unsigned short*)(pool + 51200);   // pitch 132
  unsigned short* G  = (unsigned short*)(pool + 51200);   // pitch 132
  int*   f1s    = (int*)(pool + 68096);
  int*   f2s    = (int*)(pool + 68352);
  float* validf = (float*)(pool + 68608);

  const int t = threadIdx.x;
  const int lane = t & 63;
  const int w = t >> 6;   // 0..7
  const int l15 = lane & 15;
  const int l4 = lane >> 4;
  const int eg0 = blockIdx.x * 64;

  if (t < 64) {
    const int eg = eg0 + t;
    const int b = eg >> 15;  // / NE
    const int r1 = e2f[2 * eg], r2 = e2f[2 * eg + 1];
    const bool v = (emask[eg] != 0) && (r1 >= 0) && (r2 >= 0);
    int f1 = r1 < 0 ? 0 : (r1 > NF - 1 ? NF - 1 : r1);
    int f2 = r2 < 0 ? 0 : (r2 > NF - 1 ? NF - 1 : r2);
    f1s[t] = b * NF + f1;
    f2s[t] = b * NF + f2;
    validf[t] = v ? 1.0f : 0.0f;
  }
  __syncthreads();

  // ---- staging: 16B chunks, coalesced global, b128 LDS stores ----
  for (int k = 0; k < 2; ++k) {  // E rows
    const int c = k * 512 + t, row = c >> 4, j = c & 15;
    const float* s = Efeat + (size_t)(eg0 + row) * DD + j * 8;
    *(bf16x8*)(Xe + row * 136 + j * 8) =
        pack8(*(const float4*)s, *(const float4*)(s + 4));
  }
  for (int k = 0; k < 2; ++k) {  // F1 gathered rows
    const int c = k * 512 + t, row = c >> 4, j = c & 15;
    const float* s1 = Ffeat + (size_t)f1s[row] * DD + j * 8;
    *(bf16x8*)(Xf + row * 264 + j * 8) =
        pack8(*(const float4*)s1, *(const float4*)(s1 + 4));
  }
  for (int k = 0; k < 2; ++k) {  // F2 gathered rows
    const int c = k * 512 + t, row = c >> 4, j = c & 15;
    const float* s2 = Ffeat + (size_t)f2s[row] * DD + j * 8;
    *(bf16x8*)(Xf + row * 264 + 128 + j * 8) =
        pack8(*(const float4*)s2, *(const float4*)(s2 + 4));
  }
  __syncthreads();

  f32x4 acc3[4] = {};  // gate accumulator; E-half filled during GEMM1

  // ---- GEMM1 (+ gate E-half): wave w -> GEMM1 cols [32w,32w+32), gate cols [16w,16w+16) ----
  {
    f32x4 acc[4][2] = {};
    for (int ks = 0; ks < 12; ++ks) {
      bf16x8 a[4];
      if (ks < 4) {
        const int kb = ks * 32 + (l4 << 2);
        for (int r = 0; r < 4; ++r) a[r] = ld_ab(Xe + (r * 16 + l15) * 136 + kb);
        // gate E-half reuses the same A fragments
        bf16x8 bg8 = *(const bf16x8*)(Wgf + (((w * 8 + ks) << 6) + lane) * 8);
        for (int r = 0; r < 4; ++r) acc3[r] = MFMA16(a[r], bg8, acc3[r]);
      } else {
        const int kb = (ks - 4) * 32 + (l4 << 2);
        for (int r = 0; r < 4; ++r) a[r] = ld_ab(Xf + (r * 16 + l15) * 264 + kb);
      }
      for (int n = 0; n < 2; ++n) {
        const int nt = (w << 1) + n;
        bf16x8 bfr = *(const bf16x8*)(W1f + (((nt * 12 + ks) << 6) + lane) * 8);
        for (int r = 0; r < 4; ++r) acc[r][n] = MFMA16(a[r], bfr, acc[r][n]);
      }
    }
    __syncthreads();  // Xf fully read; H may overwrite it
    for (int n = 0; n < 2; ++n) {
      const int col = (w << 5) + (n << 4) + l15;
      const float bias = b1[col];
      for (int r = 0; r < 4; ++r)
        for (int ri = 0; ri < 4; ++ri) {
          const int rw = r * 16 + (l4 << 2) + ri;
          H[rw * 260 + col] = f2bf(gelu_fast(acc[r][n][ri] + bias));
        }
    }
  }
  __syncthreads();

  // ---- GEMM2: (64x256)@(256x128), wave w -> cols [16w, 16w+16) ----
  {
    f32x4 acc2[4] = {};
    for (int ks = 0; ks < 8; ++ks) {
      const int kb = ks * 32 + (l4 << 2);
      bf16x8 a[4];
      for (int r = 0; r < 4; ++r) a[r] = ld_ab(H + (r * 16 + l15) * 260 + kb);
      bf16x8 bfr = *(const bf16x8*)(W2f + (((w * 8 + ks) << 6) + lane) * 8);
      for (int r = 0; r < 4; ++r) acc2[r] = MFMA16(a[r], bfr, acc2[r]);
    }
    __syncthreads();  // H fully read; M may overwrite it
    const int col = (w << 4) + l15;
    const float bias = b2[col];
    for (int r = 0; r < 4; ++r)
      for (int ri = 0; ri < 4; ++ri) {
        const int rw = r * 16 + (l4 << 2) + ri;
        const float mv = (acc2[r][ri] + bias) * validf[rw];
        M[rw * 132 + col] = mv;
        Mb[rw * 132 + col] = f2bf(mv);
      }
  }
  __syncthreads();

  // ---- gate msg-half: ks 4..7 read Mb; then sigmoid -> G (aliases Mb after barrier) ----
  {
    for (int ks = 4; ks < 8; ++ks) {
      const int kb = (ks - 4) * 32 + (l4 << 2);
      bf16x8 a[4];
      for (int r = 0; r < 4; ++r) a[r] = ld_ab(Mb + (r * 16 + l15) * 132 + kb);
      bf16x8 bg8 = *(const bf16x8*)(Wgf + (((w * 8 + ks) << 6) + lane) * 8);
      for (int r = 0; r < 4; ++r) acc3[r] = MFMA16(a[r], bg8, acc3[r]);
    }
    __syncthreads();  // Mb fully read; G may overwrite it
    const int col = (w << 4) + l15;
    const float bias = bg[col];
    for (int r = 0; r < 4; ++r)
      for (int ri = 0; ri < 4; ++ri) {
        const int rw = r * 16 + (l4 << 2) + ri;
        G[rw * 132 + col] = f2bf(sigmoid_fast(acc3[r][ri] + bias));
      }
  }

  // ---- prefetch residual E for the fused epilogue (global; no LDS hazard) ----
  const int rw = t >> 3, q = t & 7;  // row 0..63, 16-col chunk
  float4 e4[4];
  {
    const float* ep = Efeat + (size_t)(eg0 + rw) * DD + q * 16;
    for (int c4 = 0; c4 < 4; ++c4) e4[c4] = ((const float4*)ep)[c4];
  }
  __syncthreads();  // G complete

  // ---- fused u + LN + store (register-resident; pattern proven in k_face) ----
  {
    const float* mp = M + rw * 132 + q * 16;            // 16B-aligned
    const unsigned short* gp = G + rw * 132 + q * 16;   // 8B-aligned -> ld8
    bf16x8 g0 = ld8(gp), g1 = ld8(gp + 8);
    float u[16];
    float s = 0.f, s2 = 0.f;
    for (int c4 = 0; c4 < 4; ++c4) {
      float4 m4 = ((const float4*)mp)[c4];
      const float* ee = (const float*)&e4[c4];
      for (int jj = 0; jj < 4; ++jj) {
        const int ix = c4 * 4 + jj;
        const float gv = bf2f((unsigned short)((ix < 8) ? g0[ix] : g1[ix - 8]));
        const float v = ee[jj] + gv * ((const float*)&m4)[jj];
        u[ix] = v;
        s += v; s2 += v * v;
      }
    }
    s += __shfl_xor(s, 1); s2 += __shfl_xor(s2, 1);
    s += __shfl_xor(s, 2); s2 += __shfl_xor(s2, 2);
    s += __shfl_xor(s, 4); s2 += __shfl_xor(s2, 4);
    const float mean = s * 0.0078125f;
    const float var = s2 * 0.0078125f - mean * mean;
    const float rstd = rsqrtf(var + 1e-5f);
    float* eo = out + (size_t)MF * DD + (size_t)(eg0 + rw) * DD + q * 16;
    const float* gep = ge + q * 16;
    const float* bep = be + q * 16;
    for (int c4 = 0; c4 < 4; ++c4) {
      float4 g4 = ((const float4*)gep)[c4];
      float4 b4 = ((const float4*)bep)[c4];
      float4 o4;
      o4.x = (u[c4 * 4 + 0] - mean) * rstd * g4.x + b4.x;
      o4.y = (u[c4 * 4 + 1] - mean) * rstd * g4.y + b4.y;
      o4.z = (u[c4 * 4 + 2] - mean) * rstd * g4.z + b4.z;
      o4.w = (u[c4 * 4 + 3] - mean) * rstd * g4.w + b4.w;
      ((float4*)eo)[c4] = o4;
    }
  }
}

// ---------------- Face kernel: r7/r10 proven body + gf-F-half merged into ef1 ----------------
__global__ __launch_bounds__(512, 6) void k_face(
    const float* __restrict__ Ffeat, const int* __restrict__ fmask,
    const unsigned short* __restrict__ W1f, const float* __restrict__ b1,
    const unsigned short* __restrict__ W2f, const float* __restrict__ b2,
    const unsigned short* __restrict__ Wgf, const float* __restrict__ bg,
    const float* __restrict__ gf, const float* __restrict__ bef,
    float* __restrict__ out, const int* __restrict__ cntI) {
  __shared__ __align__(16) unsigned char pool[51712];
  unsigned short* X  = (unsigned short*)pool;             // pitch 264
  int*          lid  = (int*)(pool + 33792);              // [64][32]
  unsigned short* H  = (unsigned short*)(pool + 33792);   // pitch 136
  unsigned short* Ub = (unsigned short*)(pool + 33792);   // pitch 136
  int*   cnts = (int*)(pool + 51200);
  float* fmv  = (float*)(pool + 51456);

  const int t = threadIdx.x;
  const int lane = t & 63;
  const int w = t >> 6;
  const int l15 = lane & 15;
  const int l4 = lane >> 4;
  const int fg0 = blockIdx.x * 64;
  const int* outInt = (const int*)out;
  const float* Enew = out + (size_t)MF * DD;

  if (t < 64) {
    fmv[t] = fmask[fg0 + t] ? 1.0f : 0.0f;
    cnts[t] = cntI[fg0 + t];
  }
  for (int k = 0; k < 4; ++k) {  // stage id lists
    const int idx = k * 512 + t, row = idx >> 5, p = idx & 31;
    lid[idx] = outInt[(size_t)(fg0 + row) * DD + p];
  }
  for (int k = 0; k < 2; ++k) {  // stage F half of X
    const int c = k * 512 + t, row = c >> 4, j = c & 15;
    const float* sf = Ffeat + (size_t)(fg0 + row) * DD + j * 8;
    *(bf16x8*)(X + row * 264 + j * 8) =
        pack8(*(const float4*)sf, *(const float4*)(sf + 4));
  }
  __syncthreads();

  // ---- gather msg: parallel predicated 8-wide prefetch + rare tail ----
  {
    const int colc = t & 127;
    const int rb = t >> 7;  // 0..3
    for (int i = 0; i < 16; ++i) {
      const int row = 4 * i + rb;
      const int c = cnts[row];
      const int cl = c < CAP ? c : CAP;
      const int* lr = lid + row * 32;
      float s = 0.f;
#pragma unroll
      for (int p = 0; p < 8; ++p) {
        const int idx = (p < cl) ? lr[p] : 0;
        const float v = Enew[(size_t)idx * DD + colc];
        s += (p < cl) ? v : 0.f;
      }
      for (int p = 8; p < cl; ++p) s += Enew[(size_t)lr[p] * DD + colc];
      X[row * 264 + 128 + colc] = f2bf(s / ((float)c + 1e-8f));
    }
  }
  __syncthreads();  // msg complete; lid dead (H may overwrite)

  f32x4 acc3[4] = {};  // gate accumulator; F-half filled during ef1

  // ---- GEMM ef1 (+ gf F-half): wave w -> cols [16w,16w+16) ----
  {
    f32x4 acc[4] = {};
    for (int ks = 0; ks < 8; ++ks) {
      const int kb = ks * 32 + (l4 << 2);
      bf16x8 a[4];
      for (int r = 0; r < 4; ++r) a[r] = ld_ab(X + (r * 16 + l15) * 264 + kb);
      if (ks < 4) {  // gf F-half shares A fragments
        bf16x8 bg8 = *(const bf16x8*)(Wgf + (((w * 8 + ks) << 6) + lane) * 8);
        for (int r = 0; r < 4; ++r) acc3[r] = MFMA16(a[r], bg8, acc3[r]);
      }
      bf16x8 bfr = *(const bf16x8*)(W1f + (((w * 8 + ks) << 6) + lane) * 8);
      for (int r = 0; r < 4; ++r) acc[r] = MFMA16(a[r], bfr, acc[r]);
    }
    const int col = (w << 4) + l15;
    const float bias = b1[col];
    for (int r = 0; r < 4; ++r)
      for (int ri = 0; ri < 4; ++ri) {
        const int rw = r * 16 + (l4 << 2) + ri;
        H[rw * 136 + col] = f2bf(gelu_fast(acc[r][ri] + bias));
      }
  }
  __syncthreads();

  // ---- GEMM ef2: (64x128)@(128x128) -> Ub bf16 (in place over H) ----
  {
    f32x4 acc2[4] = {};
    for (int ks = 0; ks < 4; ++ks) {
      const int kb = ks * 32 + (l4 << 2);
      bf16x8 a[4];
      for (int r = 0; r < 4; ++r) a[r] = ld_ab(H + (r * 16 + l15) * 136 + kb);
      bf16x8 bfr = *(const bf16x8*)(W2f + (((w * 4 + ks) << 6) + lane) * 8);
      for (int r = 0; r < 4; ++r) acc2[r] = MFMA16(a[r], bfr, acc2[r]);
    }
    __syncthreads();  // H fully read; Ub overwrites same cells
    const int col = (w << 4) + l15;
    const float bias = b2[col];
    for (int r = 0; r < 4; ++r)
      for (int ri = 0; ri < 4; ++ri) {
        const int rw = r * 16 + (l4 << 2) + ri;
        Ub[rw * 136 + col] = f2bf(acc2[r][ri] + bias);
      }
  }
  __syncthreads();

  // ---- gf update-half: ks 4..7 read Ub; then gate-fold into Ub (with face mask) ----
  {
    for (int ks = 4; ks < 8; ++ks) {
      const int kb = (ks - 4) * 32 + (l4 << 2);
      bf16x8 a[4];
      for (int r = 0; r < 4; ++r) a[r] = ld_ab(Ub + (r * 16 + l15) * 136 + kb);
      bf16x8 bg8 = *(const bf16x8*)(Wgf + (((w * 8 + ks) << 6) + lane) * 8);
      for (int r = 0; r < 4; ++r) acc3[r] = MFMA16(a[r], bg8, acc3[r]);
    }
    __syncthreads();  // Ub fully read; fold rewrites in place
    const int col = (w << 4) + l15;
    const float bias = bg[col];
    for (int r = 0; r < 4; ++r)
      for (int ri = 0; ri < 4; ++ri) {
        const int rw = r * 16 + (l4 << 2) + ri;
        const int off = rw * 136 + col;
        Ub[off] = f2bf(sigmoid_fast(acc3[r][ri] + bias) * bf2f(Ub[off]) * fmv[rw]);
      }
  }
  __syncthreads();

  // ---- fused u + LN + store F_new (overwrites id-list region of out) ----
  {
    const int rw = t >> 3, q = t & 7;
    const unsigned short* xf = X + rw * 264 + q * 16;
    const unsigned short* ub = Ub + rw * 136 + q * 16;
    bf16x8 e0 = *(const bf16x8*)(xf), e1 = *(const bf16x8*)(xf + 8);
    bf16x8 m0 = *(const bf16x8*)(ub), m1 = *(const bf16x8*)(ub + 8);
    float u[16];
    float s = 0.f, s2 = 0.f;
    for (int jj = 0; jj < 8; ++jj) {
      const float v0 = bf2f((unsigned short)e0[jj]) + bf2f((unsigned short)m0[jj]);
      const float v1 = bf2f((unsigned short)e1[jj]) + bf2f((unsigned short)m1[jj]);
      u[jj] = v0; u[8 + jj] = v1;
      s += v0 + v1; s2 += v0 * v0 + v1 * v1;
    }
    s += __shfl_xor(s, 1); s2 += __shfl_xor(s2, 1);
    s += __shfl_xor(s, 2); s2 += __shfl_xor(s2, 2);
    s += __shfl_xor(s, 4); s2 += __shfl_xor(s2, 4);
    const float mean = s * 0.0078125f;
    const float var = s2 * 0.0078125f - mean * mean;
    const float rstd = rsqrtf(var + 1e-5f);
    float* fo = out + (size_t)(fg0 + rw) * DD + q * 16;
    const float* gfp = gf + q * 16;
    const float* bfp = bef + q * 16;
    for (int c4 = 0; c4 < 4; ++c4) {
      float4 g4 = ((const float4*)gfp)[c4];
      float4 b4 = ((const float4*)bfp)[c4];
      float4 o4;
      o4.x = (u[c4 * 4 + 0] - mean) * rstd * g4.x + b4.x;
      o4.y = (u[c4 * 4 + 1] - mean) * rstd * g4.y + b4.y;
      o4.z = (u[c4 * 4 + 2] - mean) * rstd * g4.z + b4.z;
      o4.w = (u[c4 * 4 + 3] - mean) * rstd * g4.w + b4.w;
      ((float4*)fo)[c4] = o4;
    }
  }
}

extern "C" void kernel_launch(void* const* d_in, const int* in_sizes, int n_in,
                              void* d_out, int out_size, void* d_ws, size_t ws_size,
                              hipStream_t stream) {
  const float* Ffeat = (const float*)d_in[0];
  const float* Efeat = (const float*)d_in[1];
  const int* e2f = (const int*)d_in[2];
  const int* fmask = (const int*)d_in[3];
  const int* emask = (const int*)d_in[4];
  const float* w_fe1 = (const float*)d_in[5];
  const float* b_fe1 = (const float*)d_in[6];
  const float* w_fe2 = (const float*)d_in[7];
  const float* b_fe2 = (const float*)d_in[8];
  const float* w_ge = (const float*)d_in[9];
  const float* b_ge = (const float*)d_in[10];
  const float* g_e = (const float*)d_in[11];
  const float* beta_e = (const float*)d_in[12];
  const float* w_ef1 = (const float*)d_in[13];
  const float* b_ef1 = (const float*)d_in[14];
  const float* w_ef2 = (const float*)d_in[15];
  const float* b_ef2 = (const float*)d_in[16];
  const float* w_gf = (const float*)d_in[17];
  const float* b_gf = (const float*)d_in[18];
  const float* g_f = (const float*)d_in[19];
  const float* beta_f = (const float*)d_in[20];

  float* out = (float*)d_out;
  int* cntI = (int*)d_ws;
  unsigned short* wbase = (unsigned short*)((char*)d_ws + (size_t)MF * sizeof(int));
  unsigned short* W1f = wbase;             // 384*256
  unsigned short* W2f = W1f + 98304;       // 256*128
  unsigned short* Wgf = W2f + 32768;       // 256*128
  unsigned short* Wef1 = Wgf + 32768;      // 256*128
  unsigned short* Wef2 = Wef1 + 32768;     // 128*128
  unsigned short* Wgff = Wef2 + 16384;     // 256*128

  hipMemsetAsync(cntI, 0, (size_t)MF * sizeof(int), stream);

  // one merged prologue launch: 960 pack blocks + 1024 fill blocks
  k_prep<<<1984, 256, 0, stream>>>(w_fe1, w_fe2, w_ge, w_ef1, w_ef2, w_gf,
                                   W1f, W2f, Wgf, Wef1, Wef2, Wgff,
                                   e2f, emask, cntI, (int*)out);

  k_edge<<<ME / 64, 512, 0, stream>>>(Efeat, Ffeat, e2f, emask, W1f, b_fe1, W2f, b_fe2,
                                      Wgf, b_ge, g_e, beta_e, out);
  k_face<<<MF / 64, 512, 0, stream>>>(Ffeat, fmask, Wef1, b_ef1, Wef2, b_ef2,
                                      Wgff, b_gf, g_f, beta_f, out, cntI);
}

// Round 15
// 391.554 us; speedup vs baseline: 1.0351x; 1.0351x over previous
//
#include <hip/hip_runtime.h>

#define NB 8
#define NF 16384
#define NE 32768
#define DD 128

static constexpr int ME = NB * NE;  // 262144 edges
static constexpr int MF = NB * NF;  // 131072 faces
static constexpr int CAP = 32;      // face bucket capacity (max deg ~ Poisson(4) << 32)

typedef short bf16x8 __attribute__((ext_vector_type(8)));
typedef float f32x4 __attribute__((ext_vector_type(4)));

#define MFMA16(a, b, c) __builtin_amdgcn_mfma_f32_16x16x32_bf16((a), (b), (c), 0, 0, 0)

// hardware f32->bf16 RNE
static __device__ __forceinline__ unsigned short f2bf(float f) {
  __bf16 h = (__bf16)f;
  return __builtin_bit_cast(unsigned short, h);
}
static __device__ __forceinline__ float bf2f(unsigned short h) {
  union { unsigned u; float f; } v; v.u = ((unsigned)h) << 16;
  return v.f;
}
static __device__ __forceinline__ bf16x8 pack8(float4 a, float4 b) {
  bf16x8 r;
  r[0] = (short)f2bf(a.x); r[1] = (short)f2bf(a.y);
  r[2] = (short)f2bf(a.z); r[3] = (short)f2bf(a.w);
  r[4] = (short)f2bf(b.x); r[5] = (short)f2bf(b.y);
  r[6] = (short)f2bf(b.z); r[7] = (short)f2bf(b.w);
  return r;
}

// A/B fragment: elements j0..3 at k=kb..kb+3, j4..7 at k=kb+16..kb+19
static __device__ __forceinline__ bf16x8 ld_ab(const unsigned short* p) {
  union { unsigned long long q[2]; bf16x8 v; } u;
  u.q[0] = *(const unsigned long long*)(p);
  u.q[1] = *(const unsigned long long*)(p + 16);
  return u.v;
}

// tanh-form GELU via hw exp (|err vs erf-GELU| <= ~6e-4)
static __device__ __forceinline__ float gelu_fast(float x) {
  const float z = x * (1.5957691216f + 0.0713548163f * x * x);
  return __fdividef(x, 1.0f + __expf(-z));
}
static __device__ __forceinline__ float sigmoid_fast(float x) {
  return __fdividef(1.0f, 1.0f + __expf(-x));
}

// ---- merged prologue: 6 weight packs (blocks 0..959) + bucket fill (960..1983) ----
__global__ void k_prep(const float* __restrict__ w_fe1, const float* __restrict__ w_fe2,
                       const float* __restrict__ w_ge, const float* __restrict__ w_ef1,
                       const float* __restrict__ w_ef2, const float* __restrict__ w_gf,
                       unsigned short* __restrict__ W1f, unsigned short* __restrict__ W2f,
                       unsigned short* __restrict__ Wgf, unsigned short* __restrict__ Wef1,
                       unsigned short* __restrict__ Wef2, unsigned short* __restrict__ Wgff,
                       const int* __restrict__ e2f, const int* __restrict__ emask,
                       int* __restrict__ cntI, int* __restrict__ outInt) {
  const int b = blockIdx.x;
  if (b < 960) {
    const float* W; unsigned short* Wf; int K, N, base;
    if (b < 384)      { W = w_fe1; Wf = W1f;  K = 384; N = 256; base = 0; }
    else if (b < 512) { W = w_fe2; Wf = W2f;  K = 256; N = 128; base = 384; }
    else if (b < 640) { W = w_ge;  Wf = Wgf;  K = 256; N = 128; base = 512; }
    else if (b < 768) { W = w_ef1; Wf = Wef1; K = 256; N = 128; base = 640; }
    else if (b < 832) { W = w_ef2; Wf = Wef2; K = 128; N = 128; base = 768; }
    else              { W = w_gf;  Wf = Wgff; K = 256; N = 128; base = 832; }
    const int idx = (b - base) * 256 + threadIdx.x;
    const int j = idx & 7, lane = (idx >> 3) & 63, rest = idx >> 9;
    const int KS = K >> 5, ks = rest % KS, nt = rest / KS;
    const int col = nt * 16 + (lane & 15);
    const int kk = ks * 32 + ((j >> 2) << 4) + ((lane >> 4) << 2) + (j & 3);
    Wf[idx] = f2bf(W[kk * N + col]);
  } else {
    const int eg = (b - 960) * 256 + threadIdx.x;
    const int r1 = e2f[2 * eg], r2 = e2f[2 * eg + 1];
    if (!(emask[eg] != 0 && r1 >= 0 && r2 >= 0)) return;
    const int bb = eg >> 15;
    const int f1 = r1 > NF - 1 ? NF - 1 : r1;
    const int f2 = r2 > NF - 1 ? NF - 1 : r2;
    const int i1 = bb * NF + f1, i2 = bb * NF + f2;
    const int p1 = atomicAdd(cntI + i1, 1);
    if (p1 < CAP) outInt[(size_t)i1 * DD + p1] = eg;
    const int p2 = atomicAdd(cntI + i2, 1);
    if (p2 < CAP) outInt[(size_t)i2 * DD + p2] = eg;
  }
}

// ---------------- k_msg: edges GEMM1+GELU+GEMM2 -> msg to global (out E region).
// 64 edges/block, 8 waves, 2 blocks/CU (pool padded to pin occupancy).
// Single LDS alias (Xf -> H), identical to k_face's proven pattern.
__global__ __launch_bounds__(512, 4) void k_msg(
    const float* __restrict__ Efeat, const float* __restrict__ Ffeat,
    const int* __restrict__ e2f, const int* __restrict__ emask,
    const unsigned short* __restrict__ W1f, const float* __restrict__ b1,
    const unsigned short* __restrict__ W2f, const float* __restrict__ b2,
    float* __restrict__ out) {
  __shared__ __align__(16) unsigned char pool[69376];  // layout uses 51968; padded
  unsigned short* Xe = (unsigned short*)pool;             // pitch 136 (17408)
  unsigned short* Xf = (unsigned short*)(pool + 17408);   // pitch 264 (33792)
  unsigned short* H  = (unsigned short*)(pool + 17408);   // pitch 260 (aliases Xf)
  int*   f1s    = (int*)(pool + 51200);
  int*   f2s    = (int*)(pool + 51456);
  float* validf = (float*)(pool + 51712);

  const int t = threadIdx.x;
  const int lane = t & 63;
  const int w = t >> 6;   // 0..7
  const int l15 = lane & 15;
  const int l4 = lane >> 4;
  const int eg0 = blockIdx.x * 64;

  if (t < 64) {
    const int eg = eg0 + t;
    const int b = eg >> 15;  // / NE
    const int r1 = e2f[2 * eg], r2 = e2f[2 * eg + 1];
    const bool v = (emask[eg] != 0) && (r1 >= 0) && (r2 >= 0);
    int f1 = r1 < 0 ? 0 : (r1 > NF - 1 ? NF - 1 : r1);
    int f2 = r2 < 0 ? 0 : (r2 > NF - 1 ? NF - 1 : r2);
    f1s[t] = b * NF + f1;
    f2s[t] = b * NF + f2;
    validf[t] = v ? 1.0f : 0.0f;
  }
  __syncthreads();

  // ---- staging: 16B chunks, coalesced global, b128 LDS stores ----
  for (int k = 0; k < 2; ++k) {  // E rows (block-contiguous in global)
    const int c = k * 512 + t, row = c >> 4, j = c & 15;
    const float* s = Efeat + (size_t)(eg0 + row) * DD + j * 8;
    *(bf16x8*)(Xe + row * 136 + j * 8) =
        pack8(*(const float4*)s, *(const float4*)(s + 4));
  }
  for (int k = 0; k < 2; ++k) {  // F1 gathered rows
    const int c = k * 512 + t, row = c >> 4, j = c & 15;
    const float* s1 = Ffeat + (size_t)f1s[row] * DD + j * 8;
    *(bf16x8*)(Xf + row * 264 + j * 8) =
        pack8(*(const float4*)s1, *(const float4*)(s1 + 4));
  }
  for (int k = 0; k < 2; ++k) {  // F2 gathered rows
    const int c = k * 512 + t, row = c >> 4, j = c & 15;
    const float* s2 = Ffeat + (size_t)f2s[row] * DD + j * 8;
    *(bf16x8*)(Xf + row * 264 + 128 + j * 8) =
        pack8(*(const float4*)s2, *(const float4*)(s2 + 4));
  }
  __syncthreads();

  // ---- GEMM1: (64x384)@(384x256), wave w -> cols [32w, 32w+32) ----
  {
    f32x4 acc[4][2] = {};
    for (int ks = 0; ks < 12; ++ks) {
      bf16x8 a[4];
      if (ks < 4) {
        const int kb = ks * 32 + (l4 << 2);
        for (int r = 0; r < 4; ++r) a[r] = ld_ab(Xe + (r * 16 + l15) * 136 + kb);
      } else {
        const int kb = (ks - 4) * 32 + (l4 << 2);
        for (int r = 0; r < 4; ++r) a[r] = ld_ab(Xf + (r * 16 + l15) * 264 + kb);
      }
      for (int n = 0; n < 2; ++n) {
        const int nt = (w << 1) + n;
        bf16x8 bfr = *(const bf16x8*)(W1f + (((nt * 12 + ks) << 6) + lane) * 8);
        for (int r = 0; r < 4; ++r) acc[r][n] = MFMA16(a[r], bfr, acc[r][n]);
      }
    }
    __syncthreads();  // Xf fully read; H may overwrite it
    for (int n = 0; n < 2; ++n) {
      const int col = (w << 5) + (n << 4) + l15;
      const float bias = b1[col];
      for (int r = 0; r < 4; ++r)
        for (int ri = 0; ri < 4; ++ri) {
          const int rw = r * 16 + (l4 << 2) + ri;
          H[rw * 260 + col] = f2bf(gelu_fast(acc[r][n][ri] + bias));
        }
    }
  }
  __syncthreads();

  // ---- GEMM2: (64x256)@(256x128), wave w -> cols [16w, 16w+16);
  //      epilogue: msg*valid straight to global (fragment-mapped fp32 stores,
  //      16 consecutive cols per 16-lane group = full 64B segments) ----
  {
    f32x4 acc2[4] = {};
    for (int ks = 0; ks < 8; ++ks) {
      const int kb = ks * 32 + (l4 << 2);
      bf16x8 a[4];
      for (int r = 0; r < 4; ++r) a[r] = ld_ab(H + (r * 16 + l15) * 260 + kb);
      bf16x8 bfr = *(const bf16x8*)(W2f + (((w * 8 + ks) << 6) + lane) * 8);
      for (int r = 0; r < 4; ++r) acc2[r] = MFMA16(a[r], bfr, acc2[r]);
    }
    const int col = (w << 4) + l15;
    const float bias = b2[col];
    float* mout = out + (size_t)MF * DD;
    for (int r = 0; r < 4; ++r)
      for (int ri = 0; ri < 4; ++ri) {
        const int rw = r * 16 + (l4 << 2) + ri;
        mout[(size_t)(eg0 + rw) * DD + col] = (acc2[r][ri] + bias) * validf[rw];
      }
  }
}

// ---------------- k_gate: gate GEMM + residual + LN -> E_new (overwrites msg rows).
// 64 edges/block, 8 waves, 2 blocks/CU. EVERY LDS cell written at most once
// (Us RMW is thread-local) -> zero cross-thread WAR aliases.
__global__ __launch_bounds__(512, 4) void k_gate(
    const float* __restrict__ Efeat,
    const unsigned short* __restrict__ Wgf, const float* __restrict__ bg,
    const float* __restrict__ ge, const float* __restrict__ be,
    float* __restrict__ out) {
  __shared__ __align__(16) unsigned char pool[69120];
  unsigned short* Xe = (unsigned short*)pool;             // pitch 136 (17408)
  unsigned short* Mb = (unsigned short*)(pool + 17408);   // pitch 136 (17408)
  float*          Us = (float*)(pool + 34816);            // pitch 132 f32 (33792)
  float* mu = (float*)(pool + 68608);
  float* rs = (float*)(pool + 68864);

  const int t = threadIdx.x;
  const int lane = t & 63;
  const int w = t >> 6;
  const int l15 = lane & 15;
  const int l4 = lane >> 4;
  const int eg0 = blockIdx.x * 64;
  float* mout = out + (size_t)MF * DD;  // msg in, E_new out (same rows)

  // ---- staging: Xe from Efeat, Mb from msg (both written once) ----
  for (int k = 0; k < 2; ++k) {
    const int c = k * 512 + t, row = c >> 4, j = c & 15;
    const float* s = Efeat + (size_t)(eg0 + row) * DD + j * 8;
    *(bf16x8*)(Xe + row * 136 + j * 8) =
        pack8(*(const float4*)s, *(const float4*)(s + 4));
    const float* m = mout + (size_t)(eg0 + row) * DD + j * 8;
    *(bf16x8*)(Mb + row * 136 + j * 8) =
        pack8(*(const float4*)m, *(const float4*)(m + 4));
  }
  __syncthreads();

  // ---- GEMM3 (gate logits): [E | msg](64x256)@(256x128), wave w -> cols [16w,16w+16) ----
  {
    f32x4 acc3[4] = {};
    for (int ks = 0; ks < 8; ++ks) {
      bf16x8 a[4];
      if (ks < 4) {
        const int kb = ks * 32 + (l4 << 2);
        for (int r = 0; r < 4; ++r) a[r] = ld_ab(Xe + (r * 16 + l15) * 136 + kb);
      } else {
        const int kb = (ks - 4) * 32 + (l4 << 2);
        for (int r = 0; r < 4; ++r) a[r] = ld_ab(Mb + (r * 16 + l15) * 136 + kb);
      }
      bf16x8 bfr = *(const bf16x8*)(Wgf + (((w * 8 + ks) << 6) + lane) * 8);
      for (int r = 0; r < 4; ++r) acc3[r] = MFMA16(a[r], bfr, acc3[r]);
    }
    // gate fp32 into virgin Us (no region it could race with)
    const int col = (w << 4) + l15;
    const float bias = bg[col];
    for (int r = 0; r < 4; ++r)
      for (int ri = 0; ri < 4; ++ri) {
        const int rw = r * 16 + (l4 << 2) + ri;
        Us[rw * 132 + col] = sigmoid_fast(acc3[r][ri] + bias);
      }
  }
  __syncthreads();  // gates complete

  // ---- u = E + gate*msg (coalesced Efeat; thread-local RMW into Us) ----
  const int colc = t & 127;
  const int rb = t >> 7;  // wave-uniform, 0..3
  for (int i = 0; i < 16; ++i) {
    const int row = 4 * i + rb;
    const float ev = Efeat[(size_t)(eg0 + row) * DD + colc];
    const float gv = Us[row * 132 + colc];
    const float mvv = bf2f(Mb[row * 136 + colc]);
    Us[row * 132 + colc] = ev + gv * mvv;
  }
  __syncthreads();

  {  // ---- LN stats: 8 threads/row ----
    const int rw = t >> 3, q = t & 7;
    const float* ur = Us + rw * 132 + q * 16;
    float s = 0.f, s2 = 0.f;
    for (int j = 0; j < 4; ++j) {
      float4 v = *(const float4*)(ur + 4 * j);
      s += v.x + v.y + v.z + v.w;
      s2 += v.x * v.x + v.y * v.y + v.z * v.z + v.w * v.w;
    }
    s += __shfl_xor(s, 1); s2 += __shfl_xor(s2, 1);
    s += __shfl_xor(s, 2); s2 += __shfl_xor(s2, 2);
    s += __shfl_xor(s, 4); s2 += __shfl_xor(s2, 4);
    if (q == 0) {
      const float mean = s * 0.0078125f;
      const float var = s2 * 0.0078125f - mean * mean;
      mu[rw] = mean;
      rs[rw] = rsqrtf(var + 1e-5f);
    }
  }
  __syncthreads();

  // ---- epilogue: coalesced E_new store (overwrites this block's msg rows) ----
  const float gec = ge[colc], bec = be[colc];
  for (int i = 0; i < 16; ++i) {
    const int row = 4 * i + rb;  // wave-uniform
    const float o = (Us[row * 132 + colc] - mu[row]) * rs[row] * gec + bec;
    mout[(size_t)(eg0 + row) * DD + colc] = o;
  }
}

// ---------------- Face kernel: round-10 proven body (64 faces/block, 8 waves, 3 blocks/CU) ----------------
__global__ __launch_bounds__(512, 6) void k_face(
    const float* __restrict__ Ffeat, const int* __restrict__ fmask,
    const unsigned short* __restrict__ W1f, const float* __restrict__ b1,
    const unsigned short* __restrict__ W2f, const float* __restrict__ b2,
    const unsigned short* __restrict__ Wgf, const float* __restrict__ bg,
    const float* __restrict__ gf, const float* __restrict__ bef,
    float* __restrict__ out, const int* __restrict__ cntI) {
  __shared__ __align__(16) unsigned char pool[51712];
  unsigned short* X  = (unsigned short*)pool;             // pitch 264
  int*          lid  = (int*)(pool + 33792);              // [64][32]
  unsigned short* H  = (unsigned short*)(pool + 33792);   // pitch 136
  unsigned short* Ub = (unsigned short*)(pool + 33792);   // pitch 136
  int*   cnts = (int*)(pool + 51200);
  float* fmv  = (float*)(pool + 51456);

  const int t = threadIdx.x;
  const int lane = t & 63;
  const int w = t >> 6;
  const int l15 = lane & 15;
  const int l4 = lane >> 4;
  const int fg0 = blockIdx.x * 64;
  const int* outInt = (const int*)out;
  const float* Enew = out + (size_t)MF * DD;

  if (t < 64) {
    fmv[t] = fmask[fg0 + t] ? 1.0f : 0.0f;
    cnts[t] = cntI[fg0 + t];
  }
  for (int k = 0; k < 4; ++k) {  // stage id lists
    const int idx = k * 512 + t, row = idx >> 5, p = idx & 31;
    lid[idx] = outInt[(size_t)(fg0 + row) * DD + p];
  }
  for (int k = 0; k < 2; ++k) {  // stage F half of X
    const int c = k * 512 + t, row = c >> 4, j = c & 15;
    const float* sf = Ffeat + (size_t)(fg0 + row) * DD + j * 8;
    *(bf16x8*)(X + row * 264 + j * 8) =
        pack8(*(const float4*)sf, *(const float4*)(sf + 4));
  }
  __syncthreads();

  // ---- gather msg: parallel predicated 8-wide prefetch + rare tail ----
  {
    const int colc = t & 127;
    const int rb = t >> 7;  // 0..3
    for (int i = 0; i < 16; ++i) {
      const int row = 4 * i + rb;
      const int c = cnts[row];
      const int cl = c < CAP ? c : CAP;
      const int* lr = lid + row * 32;
      float s = 0.f;
#pragma unroll
      for (int p = 0; p < 8; ++p) {
        const int idx = (p < cl) ? lr[p] : 0;
        const float v = Enew[(size_t)idx * DD + colc];
        s += (p < cl) ? v : 0.f;
      }
      for (int p = 8; p < cl; ++p) s += Enew[(size_t)lr[p] * DD + colc];
      X[row * 264 + 128 + colc] = f2bf(s / ((float)c + 1e-8f));
    }
  }
  __syncthreads();  // msg complete; lid dead (H may overwrite)

  // ---- GEMM ef1: (64x256)@(256x128) -> GELU -> H, wave w -> cols [16w,16w+16) ----
  {
    f32x4 acc[4] = {};
    for (int ks = 0; ks < 8; ++ks) {
      const int kb = ks * 32 + (l4 << 2);
      bf16x8 a[4];
      for (int r = 0; r < 4; ++r) a[r] = ld_ab(X + (r * 16 + l15) * 264 + kb);
      bf16x8 bfr = *(const bf16x8*)(W1f + (((w * 8 + ks) << 6) + lane) * 8);
      for (int r = 0; r < 4; ++r) acc[r] = MFMA16(a[r], bfr, acc[r]);
    }
    const int col = (w << 4) + l15;
    const float bias = b1[col];
    for (int r = 0; r < 4; ++r)
      for (int ri = 0; ri < 4; ++ri) {
        const int rw = r * 16 + (l4 << 2) + ri;
        H[rw * 136 + col] = f2bf(gelu_fast(acc[r][ri] + bias));
      }
  }
  __syncthreads();

  // ---- GEMM ef2: (64x128)@(128x128) -> Ub bf16 (in place over H) ----
  {
    f32x4 acc2[4] = {};
    for (int ks = 0; ks < 4; ++ks) {
      const int kb = ks * 32 + (l4 << 2);
      bf16x8 a[4];
      for (int r = 0; r < 4; ++r) a[r] = ld_ab(H + (r * 16 + l15) * 136 + kb);
      bf16x8 bfr = *(const bf16x8*)(W2f + (((w * 4 + ks) << 6) + lane) * 8);
      for (int r = 0; r < 4; ++r) acc2[r] = MFMA16(a[r], bfr, acc2[r]);
    }
    __syncthreads();  // H fully read; Ub overwrites same cells
    const int col = (w << 4) + l15;
    const float bias = b2[col];
    for (int r = 0; r < 4; ++r)
      for (int ri = 0; ri < 4; ++ri) {
        const int rw = r * 16 + (l4 << 2) + ri;
        Ub[rw * 136 + col] = f2bf(acc2[r][ri] + bias);
      }
  }
  __syncthreads();

  // ---- GEMM gf: [F | update](64x256)@(256x128); then gate-fold into Ub ----
  {
    f32x4 acc3[4] = {};
    for (int ks = 0; ks < 8; ++ks) {
      bf16x8 a[4];
      if (ks < 4) {
        const int kb = ks * 32 + (l4 << 2);
        for (int r = 0; r < 4; ++r) a[r] = ld_ab(X + (r * 16 + l15) * 264 + kb);
      } else {
        const int kb = (ks - 4) * 32 + (l4 << 2);
        for (int r = 0; r < 4; ++r) a[r] = ld_ab(Ub + (r * 16 + l15) * 136 + kb);
      }
      bf16x8 bfr = *(const bf16x8*)(Wgf + (((w * 8 + ks) << 6) + lane) * 8);
      for (int r = 0; r < 4; ++r) acc3[r] = MFMA16(a[r], bfr, acc3[r]);
    }
    __syncthreads();  // Ub fully read; fold rewrites in place (with face mask)
    const int col = (w << 4) + l15;
    const float bias = bg[col];
    for (int r = 0; r < 4; ++r)
      for (int ri = 0; ri < 4; ++ri) {
        const int rw = r * 16 + (l4 << 2) + ri;
        const int off = rw * 136 + col;
        Ub[off] = f2bf(sigmoid_fast(acc3[r][ri] + bias) * bf2f(Ub[off]) * fmv[rw]);
      }
  }
  __syncthreads();

  // ---- fused u + LN + store F_new (overwrites id-list region of out) ----
  {
    const int rw = t >> 3, q = t & 7;
    const unsigned short* xf = X + rw * 264 + q * 16;
    const unsigned short* ub = Ub + rw * 136 + q * 16;
    bf16x8 e0 = *(const bf16x8*)(xf), e1 = *(const bf16x8*)(xf + 8);
    bf16x8 m0 = *(const bf16x8*)(ub), m1 = *(const bf16x8*)(ub + 8);
    float u[16];
    float s = 0.f, s2 = 0.f;
    for (int jj = 0; jj < 8; ++jj) {
      const float v0 = bf2f((unsigned short)e0[jj]) + bf2f((unsigned short)m0[jj]);
      const float v1 = bf2f((unsigned short)e1[jj]) + bf2f((unsigned short)m1[jj]);
      u[jj] = v0; u[8 + jj] = v1;
      s += v0 + v1; s2 += v0 * v0 + v1 * v1;
    }
    s += __shfl_xor(s, 1); s2 += __shfl_xor(s2, 1);
    s += __shfl_xor(s, 2); s2 += __shfl_xor(s2, 2);
    s += __shfl_xor(s, 4); s2 += __shfl_xor(s2, 4);
    const float mean = s * 0.0078125f;
    const float var = s2 * 0.0078125f - mean * mean;
    const float rstd = rsqrtf(var + 1e-5f);
    float* fo = out + (size_t)(fg0 + rw) * DD + q * 16;
    const float* gfp = gf + q * 16;
    const float* bfp = bef + q * 16;
    for (int c4 = 0; c4 < 4; ++c4) {
      float4 g4 = ((const float4*)gfp)[c4];
      float4 b4 = ((const float4*)bfp)[c4];
      float4 o4;
      o4.x = (u[c4 * 4 + 0] - mean) * rstd * g4.x + b4.x;
      o4.y = (u[c4 * 4 + 1] - mean) * rstd * g4.y + b4.y;
      o4.z = (u[c4 * 4 + 2] - mean) * rstd * g4.z + b4.z;
      o4.w = (u[c4 * 4 + 3] - mean) * rstd * g4.w + b4.w;
      ((float4*)fo)[c4] = o4;
    }
  }
}

extern "C" void kernel_launch(void* const* d_in, const int* in_sizes, int n_in,
                              void* d_out, int out_size, void* d_ws, size_t ws_size,
                              hipStream_t stream) {
  const float* Ffeat = (const float*)d_in[0];
  const float* Efeat = (const float*)d_in[1];
  const int* e2f = (const int*)d_in[2];
  const int* fmask = (const int*)d_in[3];
  const int* emask = (const int*)d_in[4];
  const float* w_fe1 = (const float*)d_in[5];
  const float* b_fe1 = (const float*)d_in[6];
  const float* w_fe2 = (const float*)d_in[7];
  const float* b_fe2 = (const float*)d_in[8];
  const float* w_ge = (const float*)d_in[9];
  const float* b_ge = (const float*)d_in[10];
  const float* g_e = (const float*)d_in[11];
  const float* beta_e = (const float*)d_in[12];
  const float* w_ef1 = (const float*)d_in[13];
  const float* b_ef1 = (const float*)d_in[14];
  const float* w_ef2 = (const float*)d_in[15];
  const float* b_ef2 = (const float*)d_in[16];
  const float* w_gf = (const float*)d_in[17];
  const float* b_gf = (const float*)d_in[18];
  const float* g_f = (const float*)d_in[19];
  const float* beta_f = (const float*)d_in[20];

  float* out = (float*)d_out;
  int* cntI = (int*)d_ws;
  unsigned short* wbase = (unsigned short*)((char*)d_ws + (size_t)MF * sizeof(int));
  unsigned short* W1f = wbase;             // 384*256
  unsigned short* W2f = W1f + 98304;       // 256*128
  unsigned short* Wgf = W2f + 32768;       // 256*128
  unsigned short* Wef1 = Wgf + 32768;      // 256*128
  unsigned short* Wef2 = Wef1 + 32768;     // 128*128
  unsigned short* Wgff = Wef2 + 16384;     // 256*128

  hipMemsetAsync(cntI, 0, (size_t)MF * sizeof(int), stream);

  // merged prologue: 960 pack blocks + 1024 fill blocks
  k_prep<<<1984, 256, 0, stream>>>(w_fe1, w_fe2, w_ge, w_ef1, w_ef2, w_gf,
                                   W1f, W2f, Wgf, Wef1, Wef2, Wgff,
                                   e2f, emask, cntI, (int*)out);

  k_msg<<<ME / 64, 512, 0, stream>>>(Efeat, Ffeat, e2f, emask, W1f, b_fe1,
                                     W2f, b_fe2, out);
  k_gate<<<ME / 64, 512, 0, stream>>>(Efeat, Wgf, b_ge, g_e, beta_e, out);
  k_face<<<MF / 64, 512, 0, stream>>>(Ffeat, fmask, Wef1, b_ef1, Wef2, b_ef2,
                                      Wgff, b_gf, g_f, beta_f, out, cntI);
}

// Round 16
// 375.937 us; speedup vs baseline: 1.0781x; 1.0415x over previous
//
#include <hip/hip_runtime.h>

#define NB 8
#define NF 16384
#define NE 32768
#define DD 128

static constexpr int ME = NB * NE;  // 262144 edges
static constexpr int MF = NB * NF;  // 131072 faces
static constexpr int CAP = 32;      // face bucket capacity (max deg ~ Poisson(4) << 32)

typedef short bf16x8 __attribute__((ext_vector_type(8)));
typedef float f32x4 __attribute__((ext_vector_type(4)));

#define MFMA16(a, b, c) __builtin_amdgcn_mfma_f32_16x16x32_bf16((a), (b), (c), 0, 0, 0)

// hardware f32->bf16 RNE
static __device__ __forceinline__ unsigned short f2bf(float f) {
  __bf16 h = (__bf16)f;
  return __builtin_bit_cast(unsigned short, h);
}
static __device__ __forceinline__ float bf2f(unsigned short h) {
  union { unsigned u; float f; } v; v.u = ((unsigned)h) << 16;
  return v.f;
}
static __device__ __forceinline__ bf16x8 pack8(float4 a, float4 b) {
  bf16x8 r;
  r[0] = (short)f2bf(a.x); r[1] = (short)f2bf(a.y);
  r[2] = (short)f2bf(a.z); r[3] = (short)f2bf(a.w);
  r[4] = (short)f2bf(b.x); r[5] = (short)f2bf(b.y);
  r[6] = (short)f2bf(b.z); r[7] = (short)f2bf(b.w);
  return r;
}

// A/B fragment: elements j0..3 at k=kb..kb+3, j4..7 at k=kb+16..kb+19
static __device__ __forceinline__ bf16x8 ld_ab(const unsigned short* p) {
  union { unsigned long long q[2]; bf16x8 v; } u;
  u.q[0] = *(const unsigned long long*)(p);
  u.q[1] = *(const unsigned long long*)(p + 16);
  return u.v;
}

// tanh-form GELU via hw exp (|err vs erf-GELU| <= ~6e-4)
static __device__ __forceinline__ float gelu_fast(float x) {
  const float z = x * (1.5957691216f + 0.0713548163f * x * x);
  return __fdividef(x, 1.0f + __expf(-z));
}
static __device__ __forceinline__ float sigmoid_fast(float x) {
  return __fdividef(1.0f, 1.0f + __expf(-x));
}

// ---- merged prologue: 6 weight packs (blocks 0..959) + bucket fill (960..1983) ----
__global__ void k_prep(const float* __restrict__ w_fe1, const float* __restrict__ w_fe2,
                       const float* __restrict__ w_ge, const float* __restrict__ w_ef1,
                       const float* __restrict__ w_ef2, const float* __restrict__ w_gf,
                       unsigned short* __restrict__ W1f, unsigned short* __restrict__ W2f,
                       unsigned short* __restrict__ Wgf, unsigned short* __restrict__ Wef1,
                       unsigned short* __restrict__ Wef2, unsigned short* __restrict__ Wgff,
                       const int* __restrict__ e2f, const int* __restrict__ emask,
                       int* __restrict__ cntI, int* __restrict__ outInt) {
  const int b = blockIdx.x;
  if (b < 960) {
    const float* W; unsigned short* Wf; int K, N, base;
    if (b < 384)      { W = w_fe1; Wf = W1f;  K = 384; N = 256; base = 0; }
    else if (b < 512) { W = w_fe2; Wf = W2f;  K = 256; N = 128; base = 384; }
    else if (b < 640) { W = w_ge;  Wf = Wgf;  K = 256; N = 128; base = 512; }
    else if (b < 768) { W = w_ef1; Wf = Wef1; K = 256; N = 128; base = 640; }
    else if (b < 832) { W = w_ef2; Wf = Wef2; K = 128; N = 128; base = 768; }
    else              { W = w_gf;  Wf = Wgff; K = 256; N = 128; base = 832; }
    const int idx = (b - base) * 256 + threadIdx.x;
    const int j = idx & 7, lane = (idx >> 3) & 63, rest = idx >> 9;
    const int KS = K >> 5, ks = rest % KS, nt = rest / KS;
    const int col = nt * 16 + (lane & 15);
    const int kk = ks * 32 + ((j >> 2) << 4) + ((lane >> 4) << 2) + (j & 3);
    Wf[idx] = f2bf(W[kk * N + col]);
  } else {
    const int eg = (b - 960) * 256 + threadIdx.x;
    const int r1 = e2f[2 * eg], r2 = e2f[2 * eg + 1];
    if (!(emask[eg] != 0 && r1 >= 0 && r2 >= 0)) return;
    const int bb = eg >> 15;
    const int f1 = r1 > NF - 1 ? NF - 1 : r1;
    const int f2 = r2 > NF - 1 ? NF - 1 : r2;
    const int i1 = bb * NF + f1, i2 = bb * NF + f2;
    const int p1 = atomicAdd(cntI + i1, 1);
    if (p1 < CAP) outInt[(size_t)i1 * DD + p1] = eg;
    const int p2 = atomicAdd(cntI + i2, 1);
    if (p2 < CAP) outInt[(size_t)i2 * DD + p2] = eg;
  }
}

// ---------------- k_msg: edges GEMM1+GELU+GEMM2 -> msg to global (out E region).
// 64 edges/block, 8 waves, 2 blocks/CU (pool padded to pin occupancy).
// Single LDS alias (Xf -> H), identical to k_face's proven pattern. [r15 verbatim]
__global__ __launch_bounds__(512, 4) void k_msg(
    const float* __restrict__ Efeat, const float* __restrict__ Ffeat,
    const int* __restrict__ e2f, const int* __restrict__ emask,
    const unsigned short* __restrict__ W1f, const float* __restrict__ b1,
    const unsigned short* __restrict__ W2f, const float* __restrict__ b2,
    float* __restrict__ out) {
  __shared__ __align__(16) unsigned char pool[69376];  // layout uses 51968; padded
  unsigned short* Xe = (unsigned short*)pool;             // pitch 136 (17408)
  unsigned short* Xf = (unsigned short*)(pool + 17408);   // pitch 264 (33792)
  unsigned short* H  = (unsigned short*)(pool + 17408);   // pitch 260 (aliases Xf)
  int*   f1s    = (int*)(pool + 51200);
  int*   f2s    = (int*)(pool + 51456);
  float* validf = (float*)(pool + 51712);

  const int t = threadIdx.x;
  const int lane = t & 63;
  const int w = t >> 6;   // 0..7
  const int l15 = lane & 15;
  const int l4 = lane >> 4;
  const int eg0 = blockIdx.x * 64;

  if (t < 64) {
    const int eg = eg0 + t;
    const int b = eg >> 15;  // / NE
    const int r1 = e2f[2 * eg], r2 = e2f[2 * eg + 1];
    const bool v = (emask[eg] != 0) && (r1 >= 0) && (r2 >= 0);
    int f1 = r1 < 0 ? 0 : (r1 > NF - 1 ? NF - 1 : r1);
    int f2 = r2 < 0 ? 0 : (r2 > NF - 1 ? NF - 1 : r2);
    f1s[t] = b * NF + f1;
    f2s[t] = b * NF + f2;
    validf[t] = v ? 1.0f : 0.0f;
  }
  __syncthreads();

  // ---- staging: 16B chunks, coalesced global, b128 LDS stores ----
  for (int k = 0; k < 2; ++k) {  // E rows (block-contiguous in global)
    const int c = k * 512 + t, row = c >> 4, j = c & 15;
    const float* s = Efeat + (size_t)(eg0 + row) * DD + j * 8;
    *(bf16x8*)(Xe + row * 136 + j * 8) =
        pack8(*(const float4*)s, *(const float4*)(s + 4));
  }
  for (int k = 0; k < 2; ++k) {  // F1 gathered rows
    const int c = k * 512 + t, row = c >> 4, j = c & 15;
    const float* s1 = Ffeat + (size_t)f1s[row] * DD + j * 8;
    *(bf16x8*)(Xf + row * 264 + j * 8) =
        pack8(*(const float4*)s1, *(const float4*)(s1 + 4));
  }
  for (int k = 0; k < 2; ++k) {  // F2 gathered rows
    const int c = k * 512 + t, row = c >> 4, j = c & 15;
    const float* s2 = Ffeat + (size_t)f2s[row] * DD + j * 8;
    *(bf16x8*)(Xf + row * 264 + 128 + j * 8) =
        pack8(*(const float4*)s2, *(const float4*)(s2 + 4));
  }
  __syncthreads();

  // ---- GEMM1: (64x384)@(384x256), wave w -> cols [32w, 32w+32) ----
  {
    f32x4 acc[4][2] = {};
    for (int ks = 0; ks < 12; ++ks) {
      bf16x8 a[4];
      if (ks < 4) {
        const int kb = ks * 32 + (l4 << 2);
        for (int r = 0; r < 4; ++r) a[r] = ld_ab(Xe + (r * 16 + l15) * 136 + kb);
      } else {
        const int kb = (ks - 4) * 32 + (l4 << 2);
        for (int r = 0; r < 4; ++r) a[r] = ld_ab(Xf + (r * 16 + l15) * 264 + kb);
      }
      for (int n = 0; n < 2; ++n) {
        const int nt = (w << 1) + n;
        bf16x8 bfr = *(const bf16x8*)(W1f + (((nt * 12 + ks) << 6) + lane) * 8);
        for (int r = 0; r < 4; ++r) acc[r][n] = MFMA16(a[r], bfr, acc[r][n]);
      }
    }
    __syncthreads();  // Xf fully read; H may overwrite it
    for (int n = 0; n < 2; ++n) {
      const int col = (w << 5) + (n << 4) + l15;
      const float bias = b1[col];
      for (int r = 0; r < 4; ++r)
        for (int ri = 0; ri < 4; ++ri) {
          const int rw = r * 16 + (l4 << 2) + ri;
          H[rw * 260 + col] = f2bf(gelu_fast(acc[r][n][ri] + bias));
        }
    }
  }
  __syncthreads();

  // ---- GEMM2: (64x256)@(256x128), wave w -> cols [16w, 16w+16);
  //      epilogue: msg*valid straight to global ----
  {
    f32x4 acc2[4] = {};
    for (int ks = 0; ks < 8; ++ks) {
      const int kb = ks * 32 + (l4 << 2);
      bf16x8 a[4];
      for (int r = 0; r < 4; ++r) a[r] = ld_ab(H + (r * 16 + l15) * 260 + kb);
      bf16x8 bfr = *(const bf16x8*)(W2f + (((w * 8 + ks) << 6) + lane) * 8);
      for (int r = 0; r < 4; ++r) acc2[r] = MFMA16(a[r], bfr, acc2[r]);
    }
    const int col = (w << 4) + l15;
    const float bias = b2[col];
    float* mout = out + (size_t)MF * DD;
    for (int r = 0; r < 4; ++r)
      for (int ri = 0; ri < 4; ++ri) {
        const int rw = r * 16 + (l4 << 2) + ri;
        mout[(size_t)(eg0 + rw) * DD + col] = (acc2[r][ri] + bias) * validf[rw];
      }
  }
}

// ---------------- k_gate: gate GEMM + residual + LN -> E_new (overwrites msg rows).
// 64 edges/block, 8 waves, 2 blocks/CU. Zero cross-thread WAR aliases.
// r16 change vs r15: u-phase residual from bf16 Xe (k_face-proven pattern)
// instead of a second global Efeat read -> one fewer 134MB HBM stream.
__global__ __launch_bounds__(512, 4) void k_gate(
    const float* __restrict__ Efeat,
    const unsigned short* __restrict__ Wgf, const float* __restrict__ bg,
    const float* __restrict__ ge, const float* __restrict__ be,
    float* __restrict__ out) {
  __shared__ __align__(16) unsigned char pool[69120];
  unsigned short* Xe = (unsigned short*)pool;             // pitch 136 (17408)
  unsigned short* Mb = (unsigned short*)(pool + 17408);   // pitch 136 (17408)
  float*          Us = (float*)(pool + 34816);            // pitch 132 f32 (33792)
  float* mu = (float*)(pool + 68608);
  float* rs = (float*)(pool + 68864);

  const int t = threadIdx.x;
  const int lane = t & 63;
  const int w = t >> 6;
  const int l15 = lane & 15;
  const int l4 = lane >> 4;
  const int eg0 = blockIdx.x * 64;
  float* mout = out + (size_t)MF * DD;  // msg in, E_new out (same rows)

  // ---- staging: Xe from Efeat, Mb from msg (both written once) ----
  for (int k = 0; k < 2; ++k) {
    const int c = k * 512 + t, row = c >> 4, j = c & 15;
    const float* s = Efeat + (size_t)(eg0 + row) * DD + j * 8;
    *(bf16x8*)(Xe + row * 136 + j * 8) =
        pack8(*(const float4*)s, *(const float4*)(s + 4));
    const float* m = mout + (size_t)(eg0 + row) * DD + j * 8;
    *(bf16x8*)(Mb + row * 136 + j * 8) =
        pack8(*(const float4*)m, *(const float4*)(m + 4));
  }
  __syncthreads();

  // ---- GEMM3 (gate logits): [E | msg](64x256)@(256x128), wave w -> cols [16w,16w+16) ----
  {
    f32x4 acc3[4] = {};
    for (int ks = 0; ks < 8; ++ks) {
      bf16x8 a[4];
      if (ks < 4) {
        const int kb = ks * 32 + (l4 << 2);
        for (int r = 0; r < 4; ++r) a[r] = ld_ab(Xe + (r * 16 + l15) * 136 + kb);
      } else {
        const int kb = (ks - 4) * 32 + (l4 << 2);
        for (int r = 0; r < 4; ++r) a[r] = ld_ab(Mb + (r * 16 + l15) * 136 + kb);
      }
      bf16x8 bfr = *(const bf16x8*)(Wgf + (((w * 8 + ks) << 6) + lane) * 8);
      for (int r = 0; r < 4; ++r) acc3[r] = MFMA16(a[r], bfr, acc3[r]);
    }
    // gate fp32 into virgin Us (no region it could race with)
    const int col = (w << 4) + l15;
    const float bias = bg[col];
    for (int r = 0; r < 4; ++r)
      for (int ri = 0; ri < 4; ++ri) {
        const int rw = r * 16 + (l4 << 2) + ri;
        Us[rw * 132 + col] = sigmoid_fast(acc3[r][ri] + bias);
      }
  }
  __syncthreads();  // gates complete

  // ---- u = E(bf16 from Xe) + gate*msg (thread-local RMW into Us) ----
  const int colc = t & 127;
  const int rb = t >> 7;  // wave-uniform, 0..3
  for (int i = 0; i < 16; ++i) {
    const int row = 4 * i + rb;
    const float ev = bf2f(Xe[row * 136 + colc]);
    const float gv = Us[row * 132 + colc];
    const float mvv = bf2f(Mb[row * 136 + colc]);
    Us[row * 132 + colc] = ev + gv * mvv;
  }
  __syncthreads();

  {  // ---- LN stats: 8 threads/row ----
    const int rw = t >> 3, q = t & 7;
    const float* ur = Us + rw * 132 + q * 16;
    float s = 0.f, s2 = 0.f;
    for (int j = 0; j < 4; ++j) {
      float4 v = *(const float4*)(ur + 4 * j);
      s += v.x + v.y + v.z + v.w;
      s2 += v.x * v.x + v.y * v.y + v.z * v.z + v.w * v.w;
    }
    s += __shfl_xor(s, 1); s2 += __shfl_xor(s2, 1);
    s += __shfl_xor(s, 2); s2 += __shfl_xor(s2, 2);
    s += __shfl_xor(s, 4); s2 += __shfl_xor(s2, 4);
    if (q == 0) {
      const float mean = s * 0.0078125f;
      const float var = s2 * 0.0078125f - mean * mean;
      mu[rw] = mean;
      rs[rw] = rsqrtf(var + 1e-5f);
    }
  }
  __syncthreads();

  // ---- epilogue: coalesced E_new store (overwrites this block's msg rows) ----
  const float gec = ge[colc], bec = be[colc];
  for (int i = 0; i < 16; ++i) {
    const int row = 4 * i + rb;  // wave-uniform
    const float o = (Us[row * 132 + colc] - mu[row]) * rs[row] * gec + bec;
    mout[(size_t)(eg0 + row) * DD + colc] = o;
  }
}

// ---------------- Face kernel: round-10 proven body (64 faces/block, 8 waves, 3 blocks/CU) ----------------
__global__ __launch_bounds__(512, 6) void k_face(
    const float* __restrict__ Ffeat, const int* __restrict__ fmask,
    const unsigned short* __restrict__ W1f, const float* __restrict__ b1,
    const unsigned short* __restrict__ W2f, const float* __restrict__ b2,
    const unsigned short* __restrict__ Wgf, const float* __restrict__ bg,
    const float* __restrict__ gf, const float* __restrict__ bef,
    float* __restrict__ out, const int* __restrict__ cntI) {
  __shared__ __align__(16) unsigned char pool[51712];
  unsigned short* X  = (unsigned short*)pool;             // pitch 264
  int*          lid  = (int*)(pool + 33792);              // [64][32]
  unsigned short* H  = (unsigned short*)(pool + 33792);   // pitch 136
  unsigned short* Ub = (unsigned short*)(pool + 33792);   // pitch 136
  int*   cnts = (int*)(pool + 51200);
  float* fmv  = (float*)(pool + 51456);

  const int t = threadIdx.x;
  const int lane = t & 63;
  const int w = t >> 6;
  const int l15 = lane & 15;
  const int l4 = lane >> 4;
  const int fg0 = blockIdx.x * 64;
  const int* outInt = (const int*)out;
  const float* Enew = out + (size_t)MF * DD;

  if (t < 64) {
    fmv[t] = fmask[fg0 + t] ? 1.0f : 0.0f;
    cnts[t] = cntI[fg0 + t];
  }
  for (int k = 0; k < 4; ++k) {  // stage id lists
    const int idx = k * 512 + t, row = idx >> 5, p = idx & 31;
    lid[idx] = outInt[(size_t)(fg0 + row) * DD + p];
  }
  for (int k = 0; k < 2; ++k) {  // stage F half of X
    const int c = k * 512 + t, row = c >> 4, j = c & 15;
    const float* sf = Ffeat + (size_t)(fg0 + row) * DD + j * 8;
    *(bf16x8*)(X + row * 264 + j * 8) =
        pack8(*(const float4*)sf, *(const float4*)(sf + 4));
  }
  __syncthreads();

  // ---- gather msg: parallel predicated 8-wide prefetch + rare tail ----
  {
    const int colc = t & 127;
    const int rb = t >> 7;  // 0..3
    for (int i = 0; i < 16; ++i) {
      const int row = 4 * i + rb;
      const int c = cnts[row];
      const int cl = c < CAP ? c : CAP;
      const int* lr = lid + row * 32;
      float s = 0.f;
#pragma unroll
      for (int p = 0; p < 8; ++p) {
        const int idx = (p < cl) ? lr[p] : 0;
        const float v = Enew[(size_t)idx * DD + colc];
        s += (p < cl) ? v : 0.f;
      }
      for (int p = 8; p < cl; ++p) s += Enew[(size_t)lr[p] * DD + colc];
      X[row * 264 + 128 + colc] = f2bf(s / ((float)c + 1e-8f));
    }
  }
  __syncthreads();  // msg complete; lid dead (H may overwrite)

  // ---- GEMM ef1: (64x256)@(256x128) -> GELU -> H, wave w -> cols [16w,16w+16) ----
  {
    f32x4 acc[4] = {};
    for (int ks = 0; ks < 8; ++ks) {
      const int kb = ks * 32 + (l4 << 2);
      bf16x8 a[4];
      for (int r = 0; r < 4; ++r) a[r] = ld_ab(X + (r * 16 + l15) * 264 + kb);
      bf16x8 bfr = *(const bf16x8*)(W1f + (((w * 8 + ks) << 6) + lane) * 8);
      for (int r = 0; r < 4; ++r) acc[r] = MFMA16(a[r], bfr, acc[r]);
    }
    const int col = (w << 4) + l15;
    const float bias = b1[col];
    for (int r = 0; r < 4; ++r)
      for (int ri = 0; ri < 4; ++ri) {
        const int rw = r * 16 + (l4 << 2) + ri;
        H[rw * 136 + col] = f2bf(gelu_fast(acc[r][ri] + bias));
      }
  }
  __syncthreads();

  // ---- GEMM ef2: (64x128)@(128x128) -> Ub bf16 (in place over H) ----
  {
    f32x4 acc2[4] = {};
    for (int ks = 0; ks < 4; ++ks) {
      const int kb = ks * 32 + (l4 << 2);
      bf16x8 a[4];
      for (int r = 0; r < 4; ++r) a[r] = ld_ab(H + (r * 16 + l15) * 136 + kb);
      bf16x8 bfr = *(const bf16x8*)(W2f + (((w * 4 + ks) << 6) + lane) * 8);
      for (int r = 0; r < 4; ++r) acc2[r] = MFMA16(a[r], bfr, acc2[r]);
    }
    __syncthreads();  // H fully read; Ub overwrites same cells
    const int col = (w << 4) + l15;
    const float bias = b2[col];
    for (int r = 0; r < 4; ++r)
      for (int ri = 0; ri < 4; ++ri) {
        const int rw = r * 16 + (l4 << 2) + ri;
        Ub[rw * 136 + col] = f2bf(acc2[r][ri] + bias);
      }
  }
  __syncthreads();

  // ---- GEMM gf: [F | update](64x256)@(256x128); then gate-fold into Ub ----
  {
    f32x4 acc3[4] = {};
    for (int ks = 0; ks < 8; ++ks) {
      bf16x8 a[4];
      if (ks < 4) {
        const int kb = ks * 32 + (l4 << 2);
        for (int r = 0; r < 4; ++r) a[r] = ld_ab(X + (r * 16 + l15) * 264 + kb);
      } else {
        const int kb = (ks - 4) * 32 + (l4 << 2);
        for (int r = 0; r < 4; ++r) a[r] = ld_ab(Ub + (r * 16 + l15) * 136 + kb);
      }
      bf16x8 bfr = *(const bf16x8*)(Wgf + (((w * 8 + ks) << 6) + lane) * 8);
      for (int r = 0; r < 4; ++r) acc3[r] = MFMA16(a[r], bfr, acc3[r]);
    }
    __syncthreads();  // Ub fully read; fold rewrites in place (with face mask)
    const int col = (w << 4) + l15;
    const float bias = bg[col];
    for (int r = 0; r < 4; ++r)
      for (int ri = 0; ri < 4; ++ri) {
        const int rw = r * 16 + (l4 << 2) + ri;
        const int off = rw * 136 + col;
        Ub[off] = f2bf(sigmoid_fast(acc3[r][ri] + bias) * bf2f(Ub[off]) * fmv[rw]);
      }
  }
  __syncthreads();

  // ---- fused u + LN + store F_new (overwrites id-list region of out) ----
  {
    const int rw = t >> 3, q = t & 7;
    const unsigned short* xf = X + rw * 264 + q * 16;
    const unsigned short* ub = Ub + rw * 136 + q * 16;
    bf16x8 e0 = *(const bf16x8*)(xf), e1 = *(const bf16x8*)(xf + 8);
    bf16x8 m0 = *(const bf16x8*)(ub), m1 = *(const bf16x8*)(ub + 8);
    float u[16];
    float s = 0.f, s2 = 0.f;
    for (int jj = 0; jj < 8; ++jj) {
      const float v0 = bf2f((unsigned short)e0[jj]) + bf2f((unsigned short)m0[jj]);
      const float v1 = bf2f((unsigned short)e1[jj]) + bf2f((unsigned short)m1[jj]);
      u[jj] = v0; u[8 + jj] = v1;
      s += v0 + v1; s2 += v0 * v0 + v1 * v1;
    }
    s += __shfl_xor(s, 1); s2 += __shfl_xor(s2, 1);
    s += __shfl_xor(s, 2); s2 += __shfl_xor(s2, 2);
    s += __shfl_xor(s, 4); s2 += __shfl_xor(s2, 4);
    const float mean = s * 0.0078125f;
    const float var = s2 * 0.0078125f - mean * mean;
    const float rstd = rsqrtf(var + 1e-5f);
    float* fo = out + (size_t)(fg0 + rw) * DD + q * 16;
    const float* gfp = gf + q * 16;
    const float* bfp = bef + q * 16;
    for (int c4 = 0; c4 < 4; ++c4) {
      float4 g4 = ((const float4*)gfp)[c4];
      float4 b4 = ((const float4*)bfp)[c4];
      float4 o4;
      o4.x = (u[c4 * 4 + 0] - mean) * rstd * g4.x + b4.x;
      o4.y = (u[c4 * 4 + 1] - mean) * rstd * g4.y + b4.y;
      o4.z = (u[c4 * 4 + 2] - mean) * rstd * g4.z + b4.z;
      o4.w = (u[c4 * 4 + 3] - mean) * rstd * g4.w + b4.w;
      ((float4*)fo)[c4] = o4;
    }
  }
}

extern "C" void kernel_launch(void* const* d_in, const int* in_sizes, int n_in,
                              void* d_out, int out_size, void* d_ws, size_t ws_size,
                              hipStream_t stream) {
  const float* Ffeat = (const float*)d_in[0];
  const float* Efeat = (const float*)d_in[1];
  const int* e2f = (const int*)d_in[2];
  const int* fmask = (const int*)d_in[3];
  const int* emask = (const int*)d_in[4];
  const float* w_fe1 = (const float*)d_in[5];
  const float* b_fe1 = (const float*)d_in[6];
  const float* w_fe2 = (const float*)d_in[7];
  const float* b_fe2 = (const float*)d_in[8];
  const float* w_ge = (const float*)d_in[9];
  const float* b_ge = (const float*)d_in[10];
  const float* g_e = (const float*)d_in[11];
  const float* beta_e = (const float*)d_in[12];
  const float* w_ef1 = (const float*)d_in[13];
  const float* b_ef1 = (const float*)d_in[14];
  const float* w_ef2 = (const float*)d_in[15];
  const float* b_ef2 = (const float*)d_in[16];
  const float* w_gf = (const float*)d_in[17];
  const float* b_gf = (const float*)d_in[18];
  const float* g_f = (const float*)d_in[19];
  const float* beta_f = (const float*)d_in[20];

  float* out = (float*)d_out;
  int* cntI = (int*)d_ws;
  unsigned short* wbase = (unsigned short*)((char*)d_ws + (size_t)MF * sizeof(int));
  unsigned short* W1f = wbase;             // 384*256
  unsigned short* W2f = W1f + 98304;       // 256*128
  unsigned short* Wgf = W2f + 32768;       // 256*128
  unsigned short* Wef1 = Wgf + 32768;      // 256*128
  unsigned short* Wef2 = Wef1 + 32768;     // 128*128
  unsigned short* Wgff = Wef2 + 16384;     // 256*128

  hipMemsetAsync(cntI, 0, (size_t)MF * sizeof(int), stream);

  // merged prologue: 960 pack blocks + 1024 fill blocks
  k_prep<<<1984, 256, 0, stream>>>(w_fe1, w_fe2, w_ge, w_ef1, w_ef2, w_gf,
                                   W1f, W2f, Wgf, Wef1, Wef2, Wgff,
                                   e2f, emask, cntI, (int*)out);

  k_msg<<<ME / 64, 512, 0, stream>>>(Efeat, Ffeat, e2f, emask, W1f, b_fe1,
                                     W2f, b_fe2, out);
  k_gate<<<ME / 64, 512, 0, stream>>>(Efeat, Wgf, b_ge, g_e, beta_e, out);
  k_face<<<MF / 64, 512, 0, stream>>>(Ffeat, fmask, Wef1, b_ef1, Wef2, b_ef2,
                                      Wgff, b_gf, g_f, beta_f, out, cntI);
}

// Round 17
// 372.784 us; speedup vs baseline: 1.0872x; 1.0085x over previous
//
#include <hip/hip_runtime.h>

#define NB 8
#define NF 16384
#define NE 32768
#define DD 128

static constexpr int ME = NB * NE;  // 262144 edges
static constexpr int MF = NB * NF;  // 131072 faces
static constexpr int CAP = 32;      // face bucket capacity (max deg ~ Poisson(4) << 32)

typedef short bf16x8 __attribute__((ext_vector_type(8)));
typedef float f32x4 __attribute__((ext_vector_type(4)));

#define MFMA16(a, b, c) __builtin_amdgcn_mfma_f32_16x16x32_bf16((a), (b), (c), 0, 0, 0)

// hardware f32->bf16 RNE
static __device__ __forceinline__ unsigned short f2bf(float f) {
  __bf16 h = (__bf16)f;
  return __builtin_bit_cast(unsigned short, h);
}
static __device__ __forceinline__ float bf2f(unsigned short h) {
  union { unsigned u; float f; } v; v.u = ((unsigned)h) << 16;
  return v.f;
}
static __device__ __forceinline__ bf16x8 pack8(float4 a, float4 b) {
  bf16x8 r;
  r[0] = (short)f2bf(a.x); r[1] = (short)f2bf(a.y);
  r[2] = (short)f2bf(a.z); r[3] = (short)f2bf(a.w);
  r[4] = (short)f2bf(b.x); r[5] = (short)f2bf(b.y);
  r[6] = (short)f2bf(b.z); r[7] = (short)f2bf(b.w);
  return r;
}

// A/B fragment: elements j0..3 at k=kb..kb+3, j4..7 at k=kb+16..kb+19
static __device__ __forceinline__ bf16x8 ld_ab(const unsigned short* p) {
  union { unsigned long long q[2]; bf16x8 v; } u;
  u.q[0] = *(const unsigned long long*)(p);
  u.q[1] = *(const unsigned long long*)(p + 16);
  return u.v;
}

// tanh-form GELU via hw exp (|err vs erf-GELU| <= ~6e-4)
static __device__ __forceinline__ float gelu_fast(float x) {
  const float z = x * (1.5957691216f + 0.0713548163f * x * x);
  return __fdividef(x, 1.0f + __expf(-z));
}
static __device__ __forceinline__ float sigmoid_fast(float x) {
  return __fdividef(1.0f, 1.0f + __expf(-x));
}

// ---- merged prologue: 6 weight packs (blocks 0..959) + bucket fill (960..1983) ----
__global__ void k_prep(const float* __restrict__ w_fe1, const float* __restrict__ w_fe2,
                       const float* __restrict__ w_ge, const float* __restrict__ w_ef1,
                       const float* __restrict__ w_ef2, const float* __restrict__ w_gf,
                       unsigned short* __restrict__ W1f, unsigned short* __restrict__ W2f,
                       unsigned short* __restrict__ Wgf, unsigned short* __restrict__ Wef1,
                       unsigned short* __restrict__ Wef2, unsigned short* __restrict__ Wgff,
                       const int* __restrict__ e2f, const int* __restrict__ emask,
                       int* __restrict__ cntI, int* __restrict__ outInt) {
  const int b = blockIdx.x;
  if (b < 960) {
    const float* W; unsigned short* Wf; int K, N, base;
    if (b < 384)      { W = w_fe1; Wf = W1f;  K = 384; N = 256; base = 0; }
    else if (b < 512) { W = w_fe2; Wf = W2f;  K = 256; N = 128; base = 384; }
    else if (b < 640) { W = w_ge;  Wf = Wgf;  K = 256; N = 128; base = 512; }
    else if (b < 768) { W = w_ef1; Wf = Wef1; K = 256; N = 128; base = 640; }
    else if (b < 832) { W = w_ef2; Wf = Wef2; K = 128; N = 128; base = 768; }
    else              { W = w_gf;  Wf = Wgff; K = 256; N = 128; base = 832; }
    const int idx = (b - base) * 256 + threadIdx.x;
    const int j = idx & 7, lane = (idx >> 3) & 63, rest = idx >> 9;
    const int KS = K >> 5, ks = rest % KS, nt = rest / KS;
    const int col = nt * 16 + (lane & 15);
    const int kk = ks * 32 + ((j >> 2) << 4) + ((lane >> 4) << 2) + (j & 3);
    Wf[idx] = f2bf(W[kk * N + col]);
  } else {
    const int eg = (b - 960) * 256 + threadIdx.x;
    const int r1 = e2f[2 * eg], r2 = e2f[2 * eg + 1];
    if (!(emask[eg] != 0 && r1 >= 0 && r2 >= 0)) return;
    const int bb = eg >> 15;
    const int f1 = r1 > NF - 1 ? NF - 1 : r1;
    const int f2 = r2 > NF - 1 ? NF - 1 : r2;
    const int i1 = bb * NF + f1, i2 = bb * NF + f2;
    const int p1 = atomicAdd(cntI + i1, 1);
    if (p1 < CAP) outInt[(size_t)i1 * DD + p1] = eg;
    const int p2 = atomicAdd(cntI + i2, 1);
    if (p2 < CAP) outInt[(size_t)i2 * DD + p2] = eg;
  }
}

// ---------------- k_msg: edges GEMM1+GELU+GEMM2 -> msg to global (out E region).
// 64 edges/block, 8 waves, 3 blocks/CU (r17: pool un-padded to true 51968 B;
// single Xf->H alias is a strict subset of k_face's 3-blk-proven pattern).
__global__ __launch_bounds__(512, 6) void k_msg(
    const float* __restrict__ Efeat, const float* __restrict__ Ffeat,
    const int* __restrict__ e2f, const int* __restrict__ emask,
    const unsigned short* __restrict__ W1f, const float* __restrict__ b1,
    const unsigned short* __restrict__ W2f, const float* __restrict__ b2,
    float* __restrict__ out) {
  __shared__ __align__(16) unsigned char pool[51968];
  unsigned short* Xe = (unsigned short*)pool;             // pitch 136 (17408)
  unsigned short* Xf = (unsigned short*)(pool + 17408);   // pitch 264 (33792)
  unsigned short* H  = (unsigned short*)(pool + 17408);   // pitch 260 (aliases Xf)
  int*   f1s    = (int*)(pool + 51200);
  int*   f2s    = (int*)(pool + 51456);
  float* validf = (float*)(pool + 51712);

  const int t = threadIdx.x;
  const int lane = t & 63;
  const int w = t >> 6;   // 0..7
  const int l15 = lane & 15;
  const int l4 = lane >> 4;
  const int eg0 = blockIdx.x * 64;

  if (t < 64) {
    const int eg = eg0 + t;
    const int b = eg >> 15;  // / NE
    const int r1 = e2f[2 * eg], r2 = e2f[2 * eg + 1];
    const bool v = (emask[eg] != 0) && (r1 >= 0) && (r2 >= 0);
    int f1 = r1 < 0 ? 0 : (r1 > NF - 1 ? NF - 1 : r1);
    int f2 = r2 < 0 ? 0 : (r2 > NF - 1 ? NF - 1 : r2);
    f1s[t] = b * NF + f1;
    f2s[t] = b * NF + f2;
    validf[t] = v ? 1.0f : 0.0f;
  }
  __syncthreads();

  // ---- staging: 16B chunks, coalesced global, b128 LDS stores ----
  for (int k = 0; k < 2; ++k) {  // E rows (block-contiguous in global)
    const int c = k * 512 + t, row = c >> 4, j = c & 15;
    const float* s = Efeat + (size_t)(eg0 + row) * DD + j * 8;
    *(bf16x8*)(Xe + row * 136 + j * 8) =
        pack8(*(const float4*)s, *(const float4*)(s + 4));
  }
  for (int k = 0; k < 2; ++k) {  // F1 gathered rows
    const int c = k * 512 + t, row = c >> 4, j = c & 15;
    const float* s1 = Ffeat + (size_t)f1s[row] * DD + j * 8;
    *(bf16x8*)(Xf + row * 264 + j * 8) =
        pack8(*(const float4*)s1, *(const float4*)(s1 + 4));
  }
  for (int k = 0; k < 2; ++k) {  // F2 gathered rows
    const int c = k * 512 + t, row = c >> 4, j = c & 15;
    const float* s2 = Ffeat + (size_t)f2s[row] * DD + j * 8;
    *(bf16x8*)(Xf + row * 264 + 128 + j * 8) =
        pack8(*(const float4*)s2, *(const float4*)(s2 + 4));
  }
  __syncthreads();

  // ---- GEMM1: (64x384)@(384x256), wave w -> cols [32w, 32w+32) ----
  {
    f32x4 acc[4][2] = {};
    for (int ks = 0; ks < 12; ++ks) {
      bf16x8 a[4];
      if (ks < 4) {
        const int kb = ks * 32 + (l4 << 2);
        for (int r = 0; r < 4; ++r) a[r] = ld_ab(Xe + (r * 16 + l15) * 136 + kb);
      } else {
        const int kb = (ks - 4) * 32 + (l4 << 2);
        for (int r = 0; r < 4; ++r) a[r] = ld_ab(Xf + (r * 16 + l15) * 264 + kb);
      }
      for (int n = 0; n < 2; ++n) {
        const int nt = (w << 1) + n;
        bf16x8 bfr = *(const bf16x8*)(W1f + (((nt * 12 + ks) << 6) + lane) * 8);
        for (int r = 0; r < 4; ++r) acc[r][n] = MFMA16(a[r], bfr, acc[r][n]);
      }
    }
    __syncthreads();  // Xf fully read; H may overwrite it
    for (int n = 0; n < 2; ++n) {
      const int col = (w << 5) + (n << 4) + l15;
      const float bias = b1[col];
      for (int r = 0; r < 4; ++r)
        for (int ri = 0; ri < 4; ++ri) {
          const int rw = r * 16 + (l4 << 2) + ri;
          H[rw * 260 + col] = f2bf(gelu_fast(acc[r][n][ri] + bias));
        }
    }
  }
  __syncthreads();

  // ---- GEMM2: (64x256)@(256x128), wave w -> cols [16w, 16w+16);
  //      epilogue: msg*valid straight to global ----
  {
    f32x4 acc2[4] = {};
    for (int ks = 0; ks < 8; ++ks) {
      const int kb = ks * 32 + (l4 << 2);
      bf16x8 a[4];
      for (int r = 0; r < 4; ++r) a[r] = ld_ab(H + (r * 16 + l15) * 260 + kb);
      bf16x8 bfr = *(const bf16x8*)(W2f + (((w * 8 + ks) << 6) + lane) * 8);
      for (int r = 0; r < 4; ++r) acc2[r] = MFMA16(a[r], bfr, acc2[r]);
    }
    const int col = (w << 4) + l15;
    const float bias = b2[col];
    float* mout = out + (size_t)MF * DD;
    for (int r = 0; r < 4; ++r)
      for (int ri = 0; ri < 4; ++ri) {
        const int rw = r * 16 + (l4 << 2) + ri;
        mout[(size_t)(eg0 + rw) * DD + col] = (acc2[r][ri] + bias) * validf[rw];
      }
  }
}

// ---------------- k_gate: gate GEMM + residual + LN -> E_new (overwrites msg rows).
// 64 edges/block, 8 waves, 2 blocks/CU. Zero cross-thread WAR aliases. [r16 verbatim]
__global__ __launch_bounds__(512, 4) void k_gate(
    const float* __restrict__ Efeat,
    const unsigned short* __restrict__ Wgf, const float* __restrict__ bg,
    const float* __restrict__ ge, const float* __restrict__ be,
    float* __restrict__ out) {
  __shared__ __align__(16) unsigned char pool[69120];
  unsigned short* Xe = (unsigned short*)pool;             // pitch 136 (17408)
  unsigned short* Mb = (unsigned short*)(pool + 17408);   // pitch 136 (17408)
  float*          Us = (float*)(pool + 34816);            // pitch 132 f32 (33792)
  float* mu = (float*)(pool + 68608);
  float* rs = (float*)(pool + 68864);

  const int t = threadIdx.x;
  const int lane = t & 63;
  const int w = t >> 6;
  const int l15 = lane & 15;
  const int l4 = lane >> 4;
  const int eg0 = blockIdx.x * 64;
  float* mout = out + (size_t)MF * DD;  // msg in, E_new out (same rows)

  // ---- staging: Xe from Efeat, Mb from msg (both written once) ----
  for (int k = 0; k < 2; ++k) {
    const int c = k * 512 + t, row = c >> 4, j = c & 15;
    const float* s = Efeat + (size_t)(eg0 + row) * DD + j * 8;
    *(bf16x8*)(Xe + row * 136 + j * 8) =
        pack8(*(const float4*)s, *(const float4*)(s + 4));
    const float* m = mout + (size_t)(eg0 + row) * DD + j * 8;
    *(bf16x8*)(Mb + row * 136 + j * 8) =
        pack8(*(const float4*)m, *(const float4*)(m + 4));
  }
  __syncthreads();

  // ---- GEMM3 (gate logits): [E | msg](64x256)@(256x128), wave w -> cols [16w,16w+16) ----
  {
    f32x4 acc3[4] = {};
    for (int ks = 0; ks < 8; ++ks) {
      bf16x8 a[4];
      if (ks < 4) {
        const int kb = ks * 32 + (l4 << 2);
        for (int r = 0; r < 4; ++r) a[r] = ld_ab(Xe + (r * 16 + l15) * 136 + kb);
      } else {
        const int kb = (ks - 4) * 32 + (l4 << 2);
        for (int r = 0; r < 4; ++r) a[r] = ld_ab(Mb + (r * 16 + l15) * 136 + kb);
      }
      bf16x8 bfr = *(const bf16x8*)(Wgf + (((w * 8 + ks) << 6) + lane) * 8);
      for (int r = 0; r < 4; ++r) acc3[r] = MFMA16(a[r], bfr, acc3[r]);
    }
    // gate fp32 into virgin Us (no region it could race with)
    const int col = (w << 4) + l15;
    const float bias = bg[col];
    for (int r = 0; r < 4; ++r)
      for (int ri = 0; ri < 4; ++ri) {
        const int rw = r * 16 + (l4 << 2) + ri;
        Us[rw * 132 + col] = sigmoid_fast(acc3[r][ri] + bias);
      }
  }
  __syncthreads();  // gates complete

  // ---- u = E(bf16 from Xe) + gate*msg (thread-local RMW into Us) ----
  const int colc = t & 127;
  const int rb = t >> 7;  // wave-uniform, 0..3
  for (int i = 0; i < 16; ++i) {
    const int row = 4 * i + rb;
    const float ev = bf2f(Xe[row * 136 + colc]);
    const float gv = Us[row * 132 + colc];
    const float mvv = bf2f(Mb[row * 136 + colc]);
    Us[row * 132 + colc] = ev + gv * mvv;
  }
  __syncthreads();

  {  // ---- LN stats: 8 threads/row ----
    const int rw = t >> 3, q = t & 7;
    const float* ur = Us + rw * 132 + q * 16;
    float s = 0.f, s2 = 0.f;
    for (int j = 0; j < 4; ++j) {
      float4 v = *(const float4*)(ur + 4 * j);
      s += v.x + v.y + v.z + v.w;
      s2 += v.x * v.x + v.y * v.y + v.z * v.z + v.w * v.w;
    }
    s += __shfl_xor(s, 1); s2 += __shfl_xor(s2, 1);
    s += __shfl_xor(s, 2); s2 += __shfl_xor(s2, 2);
    s += __shfl_xor(s, 4); s2 += __shfl_xor(s2, 4);
    if (q == 0) {
      const float mean = s * 0.0078125f;
      const float var = s2 * 0.0078125f - mean * mean;
      mu[rw] = mean;
      rs[rw] = rsqrtf(var + 1e-5f);
    }
  }
  __syncthreads();

  // ---- epilogue: coalesced E_new store (overwrites this block's msg rows) ----
  const float gec = ge[colc], bec = be[colc];
  for (int i = 0; i < 16; ++i) {
    const int row = 4 * i + rb;  // wave-uniform
    const float o = (Us[row * 132 + colc] - mu[row]) * rs[row] * gec + bec;
    mout[(size_t)(eg0 + row) * DD + colc] = o;
  }
}

// ---------------- Face kernel: round-10 proven body (64 faces/block, 8 waves, 3 blocks/CU) ----------------
__global__ __launch_bounds__(512, 6) void k_face(
    const float* __restrict__ Ffeat, const int* __restrict__ fmask,
    const unsigned short* __restrict__ W1f, const float* __restrict__ b1,
    const unsigned short* __restrict__ W2f, const float* __restrict__ b2,
    const unsigned short* __restrict__ Wgf, const float* __restrict__ bg,
    const float* __restrict__ gf, const float* __restrict__ bef,
    float* __restrict__ out, const int* __restrict__ cntI) {
  __shared__ __align__(16) unsigned char pool[51712];
  unsigned short* X  = (unsigned short*)pool;             // pitch 264
  int*          lid  = (int*)(pool + 33792);              // [64][32]
  unsigned short* H  = (unsigned short*)(pool + 33792);   // pitch 136
  unsigned short* Ub = (unsigned short*)(pool + 33792);   // pitch 136
  int*   cnts = (int*)(pool + 51200);
  float* fmv  = (float*)(pool + 51456);

  const int t = threadIdx.x;
  const int lane = t & 63;
  const int w = t >> 6;
  const int l15 = lane & 15;
  const int l4 = lane >> 4;
  const int fg0 = blockIdx.x * 64;
  const int* outInt = (const int*)out;
  const float* Enew = out + (size_t)MF * DD;

  if (t < 64) {
    fmv[t] = fmask[fg0 + t] ? 1.0f : 0.0f;
    cnts[t] = cntI[fg0 + t];
  }
  for (int k = 0; k < 4; ++k) {  // stage id lists
    const int idx = k * 512 + t, row = idx >> 5, p = idx & 31;
    lid[idx] = outInt[(size_t)(fg0 + row) * DD + p];
  }
  for (int k = 0; k < 2; ++k) {  // stage F half of X
    const int c = k * 512 + t, row = c >> 4, j = c & 15;
    const float* sf = Ffeat + (size_t)(fg0 + row) * DD + j * 8;
    *(bf16x8*)(X + row * 264 + j * 8) =
        pack8(*(const float4*)sf, *(const float4*)(sf + 4));
  }
  __syncthreads();

  // ---- gather msg: parallel predicated 8-wide prefetch + rare tail ----
  {
    const int colc = t & 127;
    const int rb = t >> 7;  // 0..3
    for (int i = 0; i < 16; ++i) {
      const int row = 4 * i + rb;
      const int c = cnts[row];
      const int cl = c < CAP ? c : CAP;
      const int* lr = lid + row * 32;
      float s = 0.f;
#pragma unroll
      for (int p = 0; p < 8; ++p) {
        const int idx = (p < cl) ? lr[p] : 0;
        const float v = Enew[(size_t)idx * DD + colc];
        s += (p < cl) ? v : 0.f;
      }
      for (int p = 8; p < cl; ++p) s += Enew[(size_t)lr[p] * DD + colc];
      X[row * 264 + 128 + colc] = f2bf(s / ((float)c + 1e-8f));
    }
  }
  __syncthreads();  // msg complete; lid dead (H may overwrite)

  // ---- GEMM ef1: (64x256)@(256x128) -> GELU -> H, wave w -> cols [16w,16w+16) ----
  {
    f32x4 acc[4] = {};
    for (int ks = 0; ks < 8; ++ks) {
      const int kb = ks * 32 + (l4 << 2);
      bf16x8 a[4];
      for (int r = 0; r < 4; ++r) a[r] = ld_ab(X + (r * 16 + l15) * 264 + kb);
      bf16x8 bfr = *(const bf16x8*)(W1f + (((w * 8 + ks) << 6) + lane) * 8);
      for (int r = 0; r < 4; ++r) acc[r] = MFMA16(a[r], bfr, acc[r]);
    }
    const int col = (w << 4) + l15;
    const float bias = b1[col];
    for (int r = 0; r < 4; ++r)
      for (int ri = 0; ri < 4; ++ri) {
        const int rw = r * 16 + (l4 << 2) + ri;
        H[rw * 136 + col] = f2bf(gelu_fast(acc[r][ri] + bias));
      }
  }
  __syncthreads();

  // ---- GEMM ef2: (64x128)@(128x128) -> Ub bf16 (in place over H) ----
  {
    f32x4 acc2[4] = {};
    for (int ks = 0; ks < 4; ++ks) {
      const int kb = ks * 32 + (l4 << 2);
      bf16x8 a[4];
      for (int r = 0; r < 4; ++r) a[r] = ld_ab(H + (r * 16 + l15) * 136 + kb);
      bf16x8 bfr = *(const bf16x8*)(W2f + (((w * 4 + ks) << 6) + lane) * 8);
      for (int r = 0; r < 4; ++r) acc2[r] = MFMA16(a[r], bfr, acc2[r]);
    }
    __syncthreads();  // H fully read; Ub overwrites same cells
    const int col = (w << 4) + l15;
    const float bias = b2[col];
    for (int r = 0; r < 4; ++r)
      for (int ri = 0; ri < 4; ++ri) {
        const int rw = r * 16 + (l4 << 2) + ri;
        Ub[rw * 136 + col] = f2bf(acc2[r][ri] + bias);
      }
  }
  __syncthreads();

  // ---- GEMM gf: [F | update](64x256)@(256x128); then gate-fold into Ub ----
  {
    f32x4 acc3[4] = {};
    for (int ks = 0; ks < 8; ++ks) {
      bf16x8 a[4];
      if (ks < 4) {
        const int kb = ks * 32 + (l4 << 2);
        for (int r = 0; r < 4; ++r) a[r] = ld_ab(X + (r * 16 + l15) * 264 + kb);
      } else {
        const int kb = (ks - 4) * 32 + (l4 << 2);
        for (int r = 0; r < 4; ++r) a[r] = ld_ab(Ub + (r * 16 + l15) * 136 + kb);
      }
      bf16x8 bfr = *(const bf16x8*)(Wgf + (((w * 8 + ks) << 6) + lane) * 8);
      for (int r = 0; r < 4; ++r) acc3[r] = MFMA16(a[r], bfr, acc3[r]);
    }
    __syncthreads();  // Ub fully read; fold rewrites in place (with face mask)
    const int col = (w << 4) + l15;
    const float bias = bg[col];
    for (int r = 0; r < 4; ++r)
      for (int ri = 0; ri < 4; ++ri) {
        const int rw = r * 16 + (l4 << 2) + ri;
        const int off = rw * 136 + col;
        Ub[off] = f2bf(sigmoid_fast(acc3[r][ri] + bias) * bf2f(Ub[off]) * fmv[rw]);
      }
  }
  __syncthreads();

  // ---- fused u + LN + store F_new (overwrites id-list region of out) ----
  {
    const int rw = t >> 3, q = t & 7;
    const unsigned short* xf = X + rw * 264 + q * 16;
    const unsigned short* ub = Ub + rw * 136 + q * 16;
    bf16x8 e0 = *(const bf16x8*)(xf), e1 = *(const bf16x8*)(xf + 8);
    bf16x8 m0 = *(const bf16x8*)(ub), m1 = *(const bf16x8*)(ub + 8);
    float u[16];
    float s = 0.f, s2 = 0.f;
    for (int jj = 0; jj < 8; ++jj) {
      const float v0 = bf2f((unsigned short)e0[jj]) + bf2f((unsigned short)m0[jj]);
      const float v1 = bf2f((unsigned short)e1[jj]) + bf2f((unsigned short)m1[jj]);
      u[jj] = v0; u[8 + jj] = v1;
      s += v0 + v1; s2 += v0 * v0 + v1 * v1;
    }
    s += __shfl_xor(s, 1); s2 += __shfl_xor(s2, 1);
    s += __shfl_xor(s, 2); s2 += __shfl_xor(s2, 2);
    s += __shfl_xor(s, 4); s2 += __shfl_xor(s2, 4);
    const float mean = s * 0.0078125f;
    const float var = s2 * 0.0078125f - mean * mean;
    const float rstd = rsqrtf(var + 1e-5f);
    float* fo = out + (size_t)(fg0 + rw) * DD + q * 16;
    const float* gfp = gf + q * 16;
    const float* bfp = bef + q * 16;
    for (int c4 = 0; c4 < 4; ++c4) {
      float4 g4 = ((const float4*)gfp)[c4];
      float4 b4 = ((const float4*)bfp)[c4];
      float4 o4;
      o4.x = (u[c4 * 4 + 0] - mean) * rstd * g4.x + b4.x;
      o4.y = (u[c4 * 4 + 1] - mean) * rstd * g4.y + b4.y;
      o4.z = (u[c4 * 4 + 2] - mean) * rstd * g4.z + b4.z;
      o4.w = (u[c4 * 4 + 3] - mean) * rstd * g4.w + b4.w;
      ((float4*)fo)[c4] = o4;
    }
  }
}

extern "C" void kernel_launch(void* const* d_in, const int* in_sizes, int n_in,
                              void* d_out, int out_size, void* d_ws, size_t ws_size,
                              hipStream_t stream) {
  const float* Ffeat = (const float*)d_in[0];
  const float* Efeat = (const float*)d_in[1];
  const int* e2f = (const int*)d_in[2];
  const int* fmask = (const int*)d_in[3];
  const int* emask = (const int*)d_in[4];
  const float* w_fe1 = (const float*)d_in[5];
  const float* b_fe1 = (const float*)d_in[6];
  const float* w_fe2 = (const float*)d_in[7];
  const float* b_fe2 = (const float*)d_in[8];
  const float* w_ge = (const float*)d_in[9];
  const float* b_ge = (const float*)d_in[10];
  const float* g_e = (const float*)d_in[11];
  const float* beta_e = (const float*)d_in[12];
  const float* w_ef1 = (const float*)d_in[13];
  const float* b_ef1 = (const float*)d_in[14];
  const float* w_ef2 = (const float*)d_in[15];
  const float* b_ef2 = (const float*)d_in[16];
  const float* w_gf = (const float*)d_in[17];
  const float* b_gf = (const float*)d_in[18];
  const float* g_f = (const float*)d_in[19];
  const float* beta_f = (const float*)d_in[20];

  float* out = (float*)d_out;
  int* cntI = (int*)d_ws;
  unsigned short* wbase = (unsigned short*)((char*)d_ws + (size_t)MF * sizeof(int));
  unsigned short* W1f = wbase;             // 384*256
  unsigned short* W2f = W1f + 98304;       // 256*128
  unsigned short* Wgf = W2f + 32768;       // 256*128
  unsigned short* Wef1 = Wgf + 32768;      // 256*128
  unsigned short* Wef2 = Wef1 + 32768;     // 128*128
  unsigned short* Wgff = Wef2 + 16384;     // 256*128

  hipMemsetAsync(cntI, 0, (size_t)MF * sizeof(int), stream);

  // merged prologue: 960 pack blocks + 1024 fill blocks
  k_prep<<<1984, 256, 0, stream>>>(w_fe1, w_fe2, w_ge, w_ef1, w_ef2, w_gf,
                                   W1f, W2f, Wgf, Wef1, Wef2, Wgff,
                                   e2f, emask, cntI, (int*)out);

  k_msg<<<ME / 64, 512, 0, stream>>>(Efeat, Ffeat, e2f, emask, W1f, b_fe1,
                                     W2f, b_fe2, out);
  k_gate<<<ME / 64, 512, 0, stream>>>(Efeat, Wgf, b_ge, g_e, beta_e, out);
  k_face<<<MF / 64, 512, 0, stream>>>(Ffeat, fmask, Wef1, b_ef1, Wef2, b_ef2,
                                      Wgff, b_gf, g_f, beta_f, out, cntI);
}